// Round 10
// baseline (1978.680 us; speedup 1.0000x reference)
//
#include <hip/hip_runtime.h>
#include <stdint.h>

#define N_NODES 50000
#define N_EDGES 200000
#define SCAN_B 512

typedef __bf16 bf16_t;
typedef bf16_t bf16x8 __attribute__((ext_vector_type(8)));
typedef float f32x4 __attribute__((ext_vector_type(4)));

__device__ __forceinline__ float bf2f(ushort h) {
  union { unsigned int u; float f; } c; c.u = ((unsigned int)h) << 16; return c.f;
}
__device__ __forceinline__ ushort f2bf(float f) {
  union { float f; unsigned int u; } c; c.f = f;
  unsigned int r = (c.u >> 16) & 1u;
  c.u += 0x7fffu + r;
  return (ushort)(c.u >> 16);
}
__device__ __forceinline__ float wave_sum(float v) {
#pragma unroll
  for (int m = 32; m > 0; m >>= 1) v += __shfl_xor(v, m, 64);
  return v;
}

// ---------------- input dtype detection + canonicalization ----------------
__global__ void detect_k(const ushort* x, unsigned int* flag) {
  int i = blockIdx.x * 256 + threadIdx.x;
  unsigned int cnt = 0;
  for (int j = i; j < 1000000; j += 64 * 256) {
    ushort v = x[j];
    if (((v & 0x7F80u) == 0x7F80u) && (v & 0x7Fu)) cnt++;
  }
  if (cnt) atomicAdd(flag, cnt);
}

__global__ void cvt_in_k(const void* src, ushort* dst, int n, const unsigned int* flag) {
  int i = blockIdx.x * 256 + threadIdx.x;
  if (i >= n) return;
  if (*flag >= 2) dst[i] = f2bf(((const float*)src)[i]);
  else            dst[i] = ((const ushort*)src)[i];
}

// permuted edge_attr convert: dst[e*8+j] = cvt(src[perm[e]*8+j])
__global__ void cvt_eattr_k(const void* src, const int* perm, ushort* dst,
                            const unsigned int* flag) {
  int i = blockIdx.x * 256 + threadIdx.x;
  if (i >= N_EDGES * 8) return;
  int e = i >> 3, j = i & 7;
  size_t o = (size_t)perm[e] * 8 + j;
  if (*flag >= 2) dst[i] = f2bf(((const float*)src)[o]);
  else            dst[i] = ((const ushort*)src)[o];
}

// Bt[n*Kpad + k] = W[(k0+k)*Wstride + n], zero-padded for k >= Ksrc
__global__ void transpose2_k(const void* W, ushort* Bt, int k0, int Ksrc, int Kpad,
                             int Wstride, const unsigned int* flag) {
  int k = blockIdx.x * 256 + threadIdx.x;
  int n = blockIdx.y;
  if (k >= Kpad) return;
  ushort v = 0;
  if (k < Ksrc) {
    if (*flag >= 2) v = f2bf(((const float*)W)[(size_t)(k0 + k) * Wstride + n]);
    else            v = ((const ushort*)W)[(size_t)(k0 + k) * Wstride + n];
  }
  Bt[(size_t)n * Kpad + k] = v;
}

// ---------------- CSR build (edge_row fixed across iterations) ----------------
__global__ void hist_k(const int* row, int* deg) {
  int e = blockIdx.x * 256 + threadIdx.x;
  if (e < N_EDGES) atomicAdd(&deg[row[e]], 1);
}
__global__ void scan_blk_k(const int* deg, int* off, int* bsum, int n) {
  __shared__ int s[SCAN_B];
  int i = blockIdx.x * SCAN_B + threadIdx.x;
  int v = (i < n) ? deg[i] : 0;
  s[threadIdx.x] = v;
  __syncthreads();
  for (int o = 1; o < SCAN_B; o <<= 1) {
    int t = (threadIdx.x >= o) ? s[threadIdx.x - o] : 0;
    __syncthreads();
    s[threadIdx.x] += t;
    __syncthreads();
  }
  if (i < n) off[i] = s[threadIdx.x] - v;  // exclusive (block-local)
  if (threadIdx.x == SCAN_B - 1) bsum[blockIdx.x] = s[SCAN_B - 1];
}
__global__ void scan_top_k(int* bsum, int nb) {  // single block, 128 threads
  __shared__ int s[128];
  int v = (threadIdx.x < nb) ? bsum[threadIdx.x] : 0;
  s[threadIdx.x] = v;
  __syncthreads();
  for (int o = 1; o < 128; o <<= 1) {
    int t = (threadIdx.x >= o) ? s[threadIdx.x - o] : 0;
    __syncthreads();
    s[threadIdx.x] += t;
    __syncthreads();
  }
  if (threadIdx.x < nb) bsum[threadIdx.x] = s[threadIdx.x] - v;  // exclusive
}
__global__ void scan_add_k(int* off, const int* bsum, int n) {
  int i = blockIdx.x * 256 + threadIdx.x;
  if (i < n) off[i] += bsum[i >> 9];
  if (i == 0) off[n] = N_EDGES;
}
__global__ void fill_k(const int* row, const int* off, int* cur, int* perm) {
  int e = blockIdx.x * 256 + threadIdx.x;
  if (e >= N_EDGES) return;
  int r = row[e];
  int p = off[r] + atomicAdd(&cur[r], 1);
  perm[p] = e;
}
__global__ void gather_rc_k(const int* row, const int* col, const int* perm,
                            int* rs, int* cs) {
  int e = blockIdx.x * 256 + threadIdx.x;
  if (e >= N_EDGES) return;
  int o = perm[e];
  rs[e] = row[o];
  cs[e] = col[o];
}

// ---------------- GEMM ----------------
// swzn > 0: flat 1-D grid, XCD-grouped: all swzn column-blocks of one
// 128-row panel map to the same XCD (blocks b with b%8 == panel%8, adjacent
// slots) so the A-panel is fetched once per L2. G = 8*ceil(nbm/8)*swzn.
// A modes: 0 strided bf16 | 4 f32 | 5 [x|nlat] | 7 x pad | 8 eattr pad
// CI: 0 zeros | 1 Cr[row]+Cc[col] | 2 Cc[col]   (direct scalar gather)
// LNN: MODE-4-only fused residual+LayerNorm epilogue -> bf16 outb
struct GemmP {
  const ushort* X;
  const ushort* L;
  const ushort* E2;
  const float*  Af;
  const int* row;
  const int* col;
  const ushort* Bt;    // [Nw][K] transposed weight
  const ushort* bias;  // [Nw] bf16
  const ushort* Cr;    // CI: row-side partials | LNN: ln gamma
  const ushort* Cc;    // CI: col-side partials | LNN: ln beta
  long cst;
  ushort* outb;  long ob_stride;
  ushort* outb2; long ob2_stride;
  ushort* outS;  long oS_stride;   // column-split secondary dest
  int nsplit;                       // cols >= nsplit go to outS
  float*  outf;  long of_stride;    // LNN: stride of p.X residual
  long e2s;
  int M, K, Nw;
  int swzn;                         // 0 = plain 2-D grid
};

template <int MODE>
__device__ __forceinline__ uint4 load_a8(const GemmP& p, int e, int kg) {
  if (MODE == 0) {
    return *(const uint4*)(p.E2 + (size_t)e * p.e2s + kg);
  } else if (MODE == 5) {
    if (kg < 160) return *(const uint4*)(p.X + (size_t)e * 160 + kg);
    return *(const uint4*)(p.L + (size_t)e * 160 + (kg - 160));
  } else if (MODE == 7) {
    if (kg < 160) return *(const uint4*)(p.X + (size_t)e * 160 + kg);
    uint4 z; z.x = z.y = z.z = z.w = 0u; return z;
  } else if (MODE == 8) {
    if (kg < 8) return *(const uint4*)(p.E2 + (size_t)e * 8);
    uint4 z; z.x = z.y = z.z = z.w = 0u; return z;
  } else {  // MODE 4: f32 source
    const float* s = p.Af + (size_t)e * p.K + kg;
    f32x4 f0 = *(const f32x4*)s;
    f32x4 f1 = *(const f32x4*)(s + 4);
    union { ushort r[8]; uint4 u; } o;
    o.r[0] = f2bf(f0[0]); o.r[1] = f2bf(f0[1]); o.r[2] = f2bf(f0[2]); o.r[3] = f2bf(f0[3]);
    o.r[4] = f2bf(f1[0]); o.r[5] = f2bf(f1[1]); o.r[6] = f2bf(f1[2]); o.r[7] = f2bf(f1[3]);
    return o.u;
  }
}

// BM=128, BK=64, BN=NT*16. Register-prefetch pipeline; LDS-staged epilogue;
// direct scalar CI gather (measured faster than LDS-staged variants).
template <int MODE, int CI, bool RELU, int NT, bool LNN>
__global__ __launch_bounds__(256) void gemm_k(GemmP p) {
  constexpr int BR = NT / 2;
  constexpr int NTC = NT * 16;
  constexpr int CIP = NTC + 8;  // padded LDS stride (16B-aligned rows)
  __shared__ __align__(16) ushort smem[9216 + 1152 * NT];
  ushort* Asm = smem;
  ushort* Bsm = smem + 9216;
  const int t = threadIdx.x;
  const int w = t >> 6;
  const int l = t & 63;
  int m0, n0;
  if (p.swzn) {
    int b = blockIdx.x;
    int panel = (b & 7) + ((b >> 3) / p.swzn) * 8;
    int nb = (b >> 3) % p.swzn;
    if (panel * 128 >= p.M) return;
    m0 = panel * 128;
    n0 = nb * NTC;
  } else {
    m0 = blockIdx.y * 128;
    n0 = blockIdx.x * NTC;
  }

  // A staging: 2 threads/row, each 64B (4x16B) contiguous
  const int srow = t >> 1;
  const int sph = (t & 1) << 5;
  int e = m0 + srow;
  if (e >= p.M) e = p.M - 1;

  // B staging: flat chunk id -> (row, k8)
  int bn_[BR], bk_[BR];
#pragma unroll
  for (int j = 0; j < BR; j++) {
    int cid = j * 256 + t;
    bn_[j] = cid >> 3;
    bk_[j] = (cid & 7) << 3;
  }

  const int mq = l & 15;
  const int qd = l >> 4;

  uint4 ar[4];
  uint4 br[BR];
  auto load_tile = [&](int k0) {
#pragma unroll
    for (int j = 0; j < 4; j++)
      ar[j] = load_a8<MODE>(p, e, k0 + sph + j * 8);
#pragma unroll
    for (int j = 0; j < BR; j++)
      br[j] = *(const uint4*)(p.Bt + (size_t)(n0 + bn_[j]) * p.K + k0 + bk_[j]);
  };

  load_tile(0);

  f32x4 acc[2][NT] = {};
  if (CI) {
    // direct per-lane scalar gather (overlaps with the A/B prefetch above)
#pragma unroll
    for (int mt = 0; mt < 2; mt++) {
#pragma unroll
      for (int i = 0; i < 4; i++) {
        int r = m0 + w * 32 + mt * 16 + qd * 4 + i;
        if (r >= p.M) r = p.M - 1;
        const ushort* pc = p.Cc + (size_t)p.col[r] * p.cst + n0 + mq;
        const ushort* pr = nullptr;
        if (CI == 1) pr = p.Cr + (size_t)p.row[r] * p.cst + n0 + mq;
#pragma unroll
        for (int nt = 0; nt < NT; nt++) {
          float v = bf2f(pc[nt * 16]);
          if (CI == 1) v += bf2f(pr[nt * 16]);
          acc[mt][nt][i] = v;
        }
      }
    }
  }

  const int kiters = p.K >> 6;
  for (int kt = 0; kt < kiters; kt++) {
    __syncthreads();
#pragma unroll
    for (int j = 0; j < 4; j++)
      *(uint4*)&Asm[srow * 72 + sph + j * 8] = ar[j];
#pragma unroll
    for (int j = 0; j < BR; j++)
      *(uint4*)&Bsm[bn_[j] * 72 + bk_[j]] = br[j];
    if (kt + 1 < kiters) load_tile((kt + 1) << 6);
    __syncthreads();
#pragma unroll
    for (int ph = 0; ph < 2; ph++) {
      uint4 ra0 = *(const uint4*)&Asm[(w * 32 + mq) * 72 + ph * 32 + qd * 8];
      uint4 ra1 = *(const uint4*)&Asm[(w * 32 + 16 + mq) * 72 + ph * 32 + qd * 8];
      bf16x8 af0 = __builtin_bit_cast(bf16x8, ra0);
      bf16x8 af1 = __builtin_bit_cast(bf16x8, ra1);
#pragma unroll
      for (int nt = 0; nt < NT; nt++) {
        uint4 rb = *(const uint4*)&Bsm[(nt * 16 + mq) * 72 + ph * 32 + qd * 8];
        bf16x8 bfv = __builtin_bit_cast(bf16x8, rb);
        acc[0][nt] = __builtin_amdgcn_mfma_f32_16x16x32_bf16(af0, bfv, acc[0][nt], 0, 0, 0);
        acc[1][nt] = __builtin_amdgcn_mfma_f32_16x16x32_bf16(af1, bfv, acc[1][nt], 0, 0, 0);
      }
    }
  }

  if (MODE == 4) {
    if (LNN) {
      // fused: nn = acc + bias; v = x + nn; LN over 160 cols; -> outb bf16
#pragma unroll
      for (int mt = 0; mt < 2; mt++) {
#pragma unroll
        for (int i = 0; i < 4; i++) {
          int r = m0 + w * 32 + mt * 16 + qd * 4 + i;
          int rc = (r < p.M) ? r : p.M - 1;
          float vals[NT];
          float s = 0.0f;
#pragma unroll
          for (int nt = 0; nt < NT; nt++) {
            int c = n0 + nt * 16 + mq;
            float v = acc[mt][nt][i] + bf2f(p.bias[c]) +
                      bf2f(p.X[(size_t)rc * p.of_stride + c]);
            vals[nt] = v; s += v;
          }
#pragma unroll
          for (int m = 1; m <= 8; m <<= 1) s += __shfl_xor(s, m, 64);
          float mu = s * (1.0f / 160.0f);
          float ss = 0.0f;
#pragma unroll
          for (int nt = 0; nt < NT; nt++) { float d = vals[nt] - mu; ss += d * d; }
#pragma unroll
          for (int m = 1; m <= 8; m <<= 1) ss += __shfl_xor(ss, m, 64);
          float inv = rsqrtf(ss * (1.0f / 160.0f) + 1e-5f);
          if (r < p.M) {
#pragma unroll
            for (int nt = 0; nt < NT; nt++) {
              int c = n0 + nt * 16 + mq;
              float o = (vals[nt] - mu) * inv * bf2f(p.Cr[c]) + bf2f(p.Cc[c]);
              p.outb[(size_t)r * p.ob_stride + c] = f2bf(o);
            }
          }
        }
      }
    } else {
#pragma unroll
      for (int mt = 0; mt < 2; mt++) {
#pragma unroll
        for (int nt = 0; nt < NT; nt++) {
          int c = n0 + nt * 16 + mq;
          float bv = bf2f(p.bias[c]);
#pragma unroll
          for (int i = 0; i < 4; i++) {
            int r = m0 + w * 32 + mt * 16 + qd * 4 + i;
            if (r >= p.M) continue;
            float v = acc[mt][nt][i] + bv;
            if (RELU) v = fmaxf(v, 0.0f);
            p.outf[(size_t)r * p.of_stride + c] = v;
          }
        }
      }
    }
  } else {
    // bf16 output: stage per-wave 32xNTC tile in LDS (pad CIP), coalesced stores
    ushort* dst = p.outb;
    long dstr = p.ob_stride;
    int nb0 = n0;
    if (p.outS && n0 >= p.nsplit) { dst = p.outS; dstr = p.oS_stride; nb0 = n0 - p.nsplit; }
    __syncthreads();  // Asm/Bsm dead
    ushort* S = smem + w * (32 * CIP);
#pragma unroll
    for (int mt = 0; mt < 2; mt++) {
#pragma unroll
      for (int nt = 0; nt < NT; nt++) {
        float bv = bf2f(p.bias[n0 + nt * 16 + mq]);
#pragma unroll
        for (int i = 0; i < 4; i++) {
          float v = acc[mt][nt][i] + bv;
          if (RELU) v = fmaxf(v, 0.0f);
          S[(mt * 16 + qd * 4 + i) * CIP + nt * 16 + mq] = f2bf(v);
        }
      }
    }
    __syncthreads();
#pragma unroll
    for (int j = 0; j < NT; j++) {
      int flat = (j * 64 + l) * 8;
      int lr = flat / NTC, cc = flat % NTC;
      int r = m0 + w * 32 + lr;
      if (r < p.M) {
        uint4 v = *(const uint4*)&S[lr * CIP + cc];
        *(uint4*)(dst + (size_t)r * dstr + nb0 + cc) = v;
        if (p.outb2) *(uint4*)(p.outb2 + (size_t)r * p.ob2_stride + n0 + cc) = v;
      }
    }
  }
}

// ---------------- fused edge GEMM1+GEMM2 ----------------
// stage1: hm = relu(Pr[rs]+Pc[cs] + el@We + eb1)   [128 rows x 256] (LDS only)
// stage2: new_edge = hm @ W2 + eb2 -> el[:,64:128]  [128 rows x 64]
// 512 threads = 8 waves x 16 rows. hm tile XOR-swizzled in LDS (64 KB).
__global__ __launch_bounds__(512) void edge12_k(
    const ushort* el, const int* rs, const int* cs, const ushort* Prc,
    const ushort* BtWe, const ushort* eb1, const ushort* Bte2, const ushort* eb2,
    ushort* elw, int M) {
  __shared__ __align__(16) ushort smem[32768];  // 64 KB
  ushort* Asm = smem;           // 128*72 = 9216
  ushort* Bsm = smem + 9216;    // 256*72 = 18432 (ends 27648)
  const int t = threadIdx.x;    // 0..511
  const int w = t >> 6;         // 0..7
  const int l = t & 63;
  const int m0 = blockIdx.x * 128;
  const int mq = l & 15;
  const int qd = l >> 4;

  // A staging: 4 threads/row, 2x16B each
  const int arow = t >> 2;           // 0..127
  const int aph = (t & 3) << 4;      // 0/16/32/48
  int ea = m0 + arow;
  if (ea >= M) ea = M - 1;
  // B staging: 256 rows x 8 k-chunks = 2048 chunks / 512 thr = 4
  int bn_[4], bk_[4];
#pragma unroll
  for (int j = 0; j < 4; j++) {
    int cid = j * 512 + t;
    bn_[j] = cid >> 3;
    bk_[j] = (cid & 7) << 3;
  }

  uint4 ar[2], br[4];
  auto load_tile = [&](int k0) {
#pragma unroll
    for (int j = 0; j < 2; j++)
      ar[j] = *(const uint4*)(el + (size_t)ea * 128 + k0 + aph + j * 8);
#pragma unroll
    for (int j = 0; j < 4; j++)
      br[j] = *(const uint4*)(BtWe + (size_t)bn_[j] * 128 + k0 + bk_[j]);
  };
  load_tile(0);

  // CI gather: rows r = m0 + w*16 + qd*4 + i; cols nt*16+mq
  f32x4 acc[16] = {};
#pragma unroll
  for (int i = 0; i < 4; i++) {
    int r = m0 + w * 16 + qd * 4 + i;
    if (r >= M) r = M - 1;
    const ushort* pc = Prc + (size_t)cs[r] * 512 + 256 + mq;
    const ushort* pr = Prc + (size_t)rs[r] * 512 + mq;
#pragma unroll
    for (int nt = 0; nt < 16; nt++)
      acc[nt][i] = bf2f(pc[nt * 16]) + bf2f(pr[nt * 16]);
  }

  // K-loop (K=128, 2 tiles)
#pragma unroll
  for (int kt = 0; kt < 2; kt++) {
    __syncthreads();
#pragma unroll
    for (int j = 0; j < 2; j++)
      *(uint4*)&Asm[arow * 72 + aph + j * 8] = ar[j];
#pragma unroll
    for (int j = 0; j < 4; j++)
      *(uint4*)&Bsm[bn_[j] * 72 + bk_[j]] = br[j];
    if (kt == 0) load_tile(64);
    __syncthreads();
#pragma unroll
    for (int ph = 0; ph < 2; ph++) {
      uint4 ra = *(const uint4*)&Asm[(w * 16 + mq) * 72 + ph * 32 + qd * 8];
      bf16x8 af = __builtin_bit_cast(bf16x8, ra);
#pragma unroll
      for (int nt = 0; nt < 16; nt++) {
        uint4 rb = *(const uint4*)&Bsm[(nt * 16 + mq) * 72 + ph * 32 + qd * 8];
        bf16x8 bfv = __builtin_bit_cast(bf16x8, rb);
        acc[nt] = __builtin_amdgcn_mfma_f32_16x16x32_bf16(af, bfv, acc[nt], 0, 0, 0);
      }
    }
  }

  // stage-1 epilogue -> wave-private LDS tile (16 rows x 256, XOR-swizzled)
  __syncthreads();  // staging dead
  ushort* S = smem + w * 4096;  // 16*256
#pragma unroll
  for (int nt = 0; nt < 16; nt++) {
    float bv = bf2f(eb1[nt * 16 + mq]);
#pragma unroll
    for (int i = 0; i < 4; i++) {
      int row = qd * 4 + i;
      float v = fmaxf(acc[nt][i] + bv, 0.0f);
      int bcol = ((nt * 16 + mq) * 2) ^ ((row & 7) << 4);
      S[row * 256 + (bcol >> 1)] = f2bf(v);
    }
  }
  __syncthreads();

  // stage-2: new_edge[16x64] = hm[16x256] @ W2[256x64]
  f32x4 acc2[4] = {};
#pragma unroll
  for (int ks = 0; ks < 8; ks++) {
    int bco = ((ks * 32 + qd * 8) * 2) ^ ((mq & 7) << 4);
    uint4 ra2 = *(const uint4*)&S[mq * 256 + (bco >> 1)];
    bf16x8 af2 = __builtin_bit_cast(bf16x8, ra2);
#pragma unroll
    for (int nt2 = 0; nt2 < 4; nt2++) {
      uint4 rb2 = *(const uint4*)(Bte2 + (size_t)(nt2 * 16 + mq) * 256 + ks * 32 + qd * 8);
      bf16x8 bf2v = __builtin_bit_cast(bf16x8, rb2);
      acc2[nt2] = __builtin_amdgcn_mfma_f32_16x16x32_bf16(af2, bf2v, acc2[nt2], 0, 0, 0);
    }
  }
  __syncthreads();  // all stage-2 reads of S done

  // epilogue-2: restage 16x64 at stride 72, coalesced uint4 stores
  ushort* S2 = smem + w * 1152;  // 16*72
#pragma unroll
  for (int nt2 = 0; nt2 < 4; nt2++) {
    float bv2 = bf2f(eb2[nt2 * 16 + mq]);
#pragma unroll
    for (int i = 0; i < 4; i++)
      S2[(qd * 4 + i) * 72 + nt2 * 16 + mq] = f2bf(acc2[nt2][i] + bv2);
  }
  __syncthreads();
#pragma unroll
  for (int j = 0; j < 2; j++) {
    int flat = (j * 64 + l) * 8;
    int lr = flat >> 6, cc = flat & 63;
    int r = m0 + w * 16 + lr;
    if (r < M)
      *(uint4*)(elw + (size_t)r * 128 + 64 + cc) = *(const uint4*)&S2[lr * 72 + cc];
  }
}

// ---------------- small kernels ----------------
__global__ void copy_u4_k(const uint4* s, uint4* d, int n) {
  int i = blockIdx.x * 256 + threadIdx.x;
  if (i < n) d[i] = s[i];
}

// Fused attention + aggregation, one wave per node; msg is row-sorted so the
// segment [off[n], off[n+1]) is contiguous.
__global__ void agg_csr_k(const ushort* msg, const ushort* att, const int* off,
                          float* agg) {
  int n = blockIdx.x * 4 + (threadIdx.x >> 6);
  int l = threadIdx.x & 63;
  if (n >= N_NODES) return;
  const int s0 = off[n], s1 = off[n + 1];
  ushort4 av = *(const ushort4*)(att + l * 4);
  const float a0 = bf2f(av.x), a1 = bf2f(av.y), a2 = bf2f(av.z), a3 = bf2f(av.w);
  float maxl = -1e30f;
  for (int j = s0; j < s1; j++) {
    ushort4 m = *(const ushort4*)(msg + (size_t)j * 256 + l * 4);
    float d = bf2f(m.x) * a0 + bf2f(m.y) * a1 + bf2f(m.z) * a2 + bf2f(m.w) * a3;
    d = wave_sum(d);
    float lg = (d > 0.0f) ? d : 0.2f * d;
    maxl = fmaxf(maxl, lg);
  }
  float den = 0.0f;
  f32x4 acc = {0.0f, 0.0f, 0.0f, 0.0f};
  for (int j = s0; j < s1; j++) {
    ushort4 m = *(const ushort4*)(msg + (size_t)j * 256 + l * 4);
    float m0 = bf2f(m.x), m1 = bf2f(m.y), m2 = bf2f(m.z), m3 = bf2f(m.w);
    float d = m0 * a0 + m1 * a1 + m2 * a2 + m3 * a3;
    d = wave_sum(d);
    float lg = (d > 0.0f) ? d : 0.2f * d;
    float ex = __expf(lg - maxl);
    den += ex;
    acc[0] += ex * m0; acc[1] += ex * m1; acc[2] += ex * m2; acc[3] += ex * m3;
  }
  float inv = 1.0f / (den + 1e-16f);
  f32x4 o = {acc[0] * inv, acc[1] * inv, acc[2] * inv, acc[3] * inv};
  *(f32x4*)(agg + (size_t)n * 256 + l * 4) = o;
}

__global__ void ln_edge_k(const ushort* g, const ushort* b, ushort* el) {
  int e = blockIdx.x * 4 + (threadIdx.x >> 6);
  int l = threadIdx.x & 63;
  if (e >= N_EDGES) return;
  float v = bf2f(el[(size_t)e * 128 + l]) + bf2f(el[(size_t)e * 128 + 64 + l]);
  float mu = wave_sum(v) * (1.0f / 64.0f);
  float d = v - mu;
  float var = wave_sum(d * d) * (1.0f / 64.0f);
  float inv = rsqrtf(var + 1e-5f);
  el[(size_t)e * 128 + 64 + l] = f2bf(d * inv * bf2f(g[l]) + bf2f(b[l]));
}

__global__ void out_node_k(const ushort* nlat, void* out, const unsigned int* flag) {
  int i = blockIdx.x * 256 + threadIdx.x;
  if (i >= N_NODES * 160) return;
  if (*flag >= 2) ((float*)out)[i] = bf2f(nlat[i]);
  else            ((ushort*)out)[i] = nlat[i];
}
// scatter sorted el back to original edge order via perm
__global__ void out_edge_k(const ushort* el, const int* perm, void* out,
                           const unsigned int* flag) {
  int i = blockIdx.x * 256 + threadIdx.x;
  if (i >= N_EDGES * 64) return;
  int e = i >> 6, c = i & 63;
  ushort v = el[(size_t)e * 128 + 64 + c];
  size_t o = (size_t)N_NODES * 160 + (size_t)perm[e] * 64 + c;
  if (*flag >= 2) ((float*)out)[o] = bf2f(v);
  else            ((ushort*)out)[o] = v;
}

// ---------------- host ----------------
extern "C" void kernel_launch(void* const* d_in, const int* in_sizes, int n_in,
                              void* d_out, int out_size, void* d_ws, size_t ws_size,
                              hipStream_t stream) {
  const void* x_r     = d_in[0];
  const void* eattr_r = d_in[1];
  const void* encW1   = d_in[2];
  const void* encb1_r = d_in[3];
  const void* encW2   = d_in[4];
  const void* encb2_r = d_in[5];
  const void* eW1     = d_in[6];
  const void* eb1_r   = d_in[7];
  const void* eW2     = d_in[8];
  const void* eb2_r   = d_in[9];
  const void* mW1     = d_in[10];
  const void* mb1_r   = d_in[11];
  const void* attv_r  = d_in[12];
  const void* nW1     = d_in[13];
  const void* nb1_r   = d_in[14];
  const void* lnng_r  = d_in[15];
  const void* lnnb_r  = d_in[16];
  const void* lneg_r  = d_in[17];
  const void* lneb_r  = d_in[18];
  const int* erow = (const int*)d_in[19];
  const int* ecol = (const int*)d_in[20];
  (void)in_sizes; (void)n_in;

  char* ws = (char*)d_ws;
  size_t off = 0;
  auto alloc = [&](size_t bytes) -> void* {
    void* p = ws + off;
    off = (off + bytes + 511) & ~(size_t)511;
    return p;
  };
  ushort* hm   = (ushort*)alloc((size_t)N_EDGES * 256 * 2);  // enc h / msg alias
  ushort* el   = (ushort*)alloc((size_t)N_EDGES * 128 * 2);
  float*  agg  = (float*)alloc((size_t)N_NODES * 256 * 4);   // eac/Penc/Prc alias
  ushort* xc   = (ushort*)alloc((size_t)N_NODES * 160 * 2);
  ushort* nlat = (ushort*)alloc((size_t)N_NODES * 160 * 2);
  ushort* Qc   = (ushort*)alloc((size_t)N_NODES * 256 * 2);  // nl @ mW1[0:320]
  int* degcur  = (int*)alloc((size_t)2 * N_NODES * 4);       // deg | cur
  int* offcsr  = (int*)alloc((size_t)(N_NODES + 1) * 4);
  int* perm    = (int*)alloc((size_t)N_EDGES * 4);
  int* rs      = (int*)alloc((size_t)N_EDGES * 4);
  int* cs      = (int*)alloc((size_t)N_EDGES * 4);
  int* bsum    = (int*)alloc((size_t)128 * 4);
  ushort* BtPe = (ushort*)alloc((size_t)256 * 192 * 2);  // [encW1_r|encW1_c]^T
  ushort* BtWenc = (ushort*)alloc((size_t)128 * 64 * 2); // encW1[320:328]^T (pad 64)
  ushort* BtE2 = (ushort*)alloc((size_t)64 * 128 * 2);
  ushort* BtPQ = (ushort*)alloc((size_t)768 * 320 * 2);  // [eW1_r|eW1_c|mW1q]^T
  ushort* BtWe = (ushort*)alloc((size_t)256 * 128 * 2);  // eW1[640:768]^T
  ushort* Bte2 = (ushort*)alloc((size_t)64 * 256 * 2);
  ushort* BtWm = (ushort*)alloc((size_t)256 * 64 * 2);   // mW1[320:384]^T
  ushort* Btn1 = (ushort*)alloc((size_t)160 * 256 * 2);
  ushort* pool = (ushort*)alloc((size_t)4096 * 2);
  unsigned int* flag = (unsigned int*)alloc(64);
  ushort* msg = hm;
  ushort* eac  = (ushort*)agg;                                    // [E,8] bf16
  ushort* Penc = (ushort*)((char*)agg + (size_t)N_EDGES * 8 * 2); // [N,256] bf16
  ushort* Prc  = (ushort*)agg;                                    // [N,512] bf16
  ushort* zb   = pool + 2048;                                     // zeros

  ushort* encb1c = pool;        ushort* encb2c = pool + 128;
  ushort* eb1c   = pool + 192;  ushort* eb2c   = pool + 448;
  ushort* mb1c   = pool + 512;  ushort* attvc  = pool + 768;
  ushort* nb1c   = pool + 1024; ushort* lnngc  = pool + 1184;
  ushort* lnnbc  = pool + 1344; ushort* lnegc  = pool + 1504;
  ushort* lnebc  = pool + 1568;

  if (off > ws_size) {
    hipMemsetAsync(d_out, 0, (size_t)out_size * 2, stream);
    return;
  }

  hipMemsetAsync(flag, 0, 64, stream);
  hipMemsetAsync(pool, 0, 4096 * 2, stream);
  hipMemsetAsync(degcur, 0, (size_t)2 * N_NODES * 4, stream);

  detect_k<<<64, 256, 0, stream>>>((const ushort*)x_r, flag);

  // CSR build (edge_row is iteration-invariant); all edge buffers stored sorted.
  {
    int* deg = degcur;
    int* cur = degcur + N_NODES;
    const int nb = (N_NODES + SCAN_B - 1) / SCAN_B;  // 98
    hist_k<<<(N_EDGES + 255) / 256, 256, 0, stream>>>(erow, deg);
    scan_blk_k<<<nb, SCAN_B, 0, stream>>>(deg, offcsr, bsum, N_NODES);
    scan_top_k<<<1, 128, 0, stream>>>(bsum, nb);
    scan_add_k<<<(N_NODES + 255) / 256, 256, 0, stream>>>(offcsr, bsum, N_NODES);
    fill_k<<<(N_EDGES + 255) / 256, 256, 0, stream>>>(erow, offcsr, cur, perm);
    gather_rc_k<<<(N_EDGES + 255) / 256, 256, 0, stream>>>(erow, ecol, perm, rs, cs);
  }

  cvt_in_k<<<(N_NODES * 160 + 255) / 256, 256, 0, stream>>>(x_r, xc, N_NODES * 160, flag);
  cvt_eattr_k<<<(N_EDGES * 8 + 255) / 256, 256, 0, stream>>>(eattr_r, perm, eac, flag);
  cvt_in_k<<<1, 256, 0, stream>>>(encb1_r, encb1c, 128, flag);
  cvt_in_k<<<1, 256, 0, stream>>>(encb2_r, encb2c, 64, flag);
  cvt_in_k<<<1, 256, 0, stream>>>(eb1_r, eb1c, 256, flag);
  cvt_in_k<<<1, 256, 0, stream>>>(eb2_r, eb2c, 64, flag);
  cvt_in_k<<<1, 256, 0, stream>>>(mb1_r, mb1c, 256, flag);
  cvt_in_k<<<1, 256, 0, stream>>>(attv_r, attvc, 256, flag);
  cvt_in_k<<<1, 256, 0, stream>>>(nb1_r, nb1c, 160, flag);
  cvt_in_k<<<1, 256, 0, stream>>>(lnng_r, lnngc, 160, flag);
  cvt_in_k<<<1, 256, 0, stream>>>(lnnb_r, lnnbc, 160, flag);
  cvt_in_k<<<1, 256, 0, stream>>>(lneg_r, lnegc, 64, flag);
  cvt_in_k<<<1, 256, 0, stream>>>(lneb_r, lnebc, 64, flag);

  // weight transposes (Bt[n][k] layout, K zero-padded to multiple of 64)
  transpose2_k<<<dim3(1, 128), 256, 0, stream>>>(encW1, BtPe,             0, 160, 192, 128, flag);
  transpose2_k<<<dim3(1, 128), 256, 0, stream>>>(encW1, BtPe + 128 * 192, 160, 160, 192, 128, flag);
  transpose2_k<<<dim3(1, 128), 256, 0, stream>>>(encW1, BtWenc,           320, 8, 64, 128, flag);
  transpose2_k<<<dim3(1, 64), 256, 0, stream>>>(encW2, BtE2, 0, 128, 128, 64, flag);
  transpose2_k<<<dim3(2, 256), 256, 0, stream>>>(eW1, BtPQ,             0, 320, 320, 256, flag);
  transpose2_k<<<dim3(2, 256), 256, 0, stream>>>(eW1, BtPQ + 256 * 320, 320, 320, 320, 256, flag);
  transpose2_k<<<dim3(2, 256), 256, 0, stream>>>(mW1, BtPQ + 512 * 320, 0, 320, 320, 256, flag);
  transpose2_k<<<dim3(1, 256), 256, 0, stream>>>(eW1, BtWe, 640, 128, 128, 256, flag);
  transpose2_k<<<dim3(1, 64), 256, 0, stream>>>(eW2, Bte2, 0, 256, 256, 64, flag);
  transpose2_k<<<dim3(1, 256), 256, 0, stream>>>(mW1, BtWm, 320, 64, 64, 256, flag);
  transpose2_k<<<dim3(1, 160), 256, 0, stream>>>(nW1, Btn1, 0, 256, 256, 160, flag);

  copy_u4_k<<<(N_NODES * 160 / 8 + 255) / 256, 256, 0, stream>>>(
      (const uint4*)xc, (uint4*)nlat, N_NODES * 160 / 8);

  const int gE = (N_EDGES + 127) / 128;  // 1563
  const int gN = (N_NODES + 127) / 128;  // 391
  const int gN8 = 8 * ((gN + 7) / 8);    // 392
  const int gE8 = 8 * ((gE + 7) / 8);    // 1568

  {  // enc pre-GEMM: Penc = x @ [encW1_r | encW1_c]   [N,256]  (XCD-swizzled)
    GemmP p{};
    p.X = xc; p.Bt = BtPe; p.bias = zb;
    p.outb = Penc; p.ob_stride = 256;
    p.M = N_NODES; p.K = 192; p.Nw = 256; p.swzn = 2;
    gemm_k<7, 0, false, 8, false><<<gN8 * 2, 256, 0, stream>>>(p);
  }
  {  // enc edge GEMM: relu(Penc_r[rs]+Penc_c[cs] + eattr@Wenc + b) -> hm [E,128]
    GemmP p{};
    p.E2 = eac; p.row = rs; p.col = cs;
    p.Cr = Penc; p.Cc = Penc + 128; p.cst = 256;
    p.Bt = BtWenc; p.bias = encb1c;
    p.outb = hm; p.ob_stride = 128;
    p.M = N_EDGES; p.K = 64; p.Nw = 128;
    gemm_k<8, 1, true, 8, false><<<dim3(1, gE), 256, 0, stream>>>(p);
  }
  {  // encoder GEMM2: hm @ [128,64] -> el[:,0:64] and el[:,64:128]
    GemmP p{};
    p.E2 = hm; p.e2s = 128; p.Bt = BtE2; p.bias = encb2c;
    p.outb = el; p.ob_stride = 128;
    p.outb2 = el + 64; p.ob2_stride = 128;
    p.M = N_EDGES; p.K = 128; p.Nw = 64;
    gemm_k<0, 0, false, 4, false><<<dim3(1, gE), 256, 0, stream>>>(p);
  }

  for (int it = 0; it < 3; it++) {
    {  // merged node pre-GEMM (XCD-swizzled): [x|nlat]@[eW1_r|eW1_c|mW1q]
      GemmP p{};
      p.X = xc; p.L = nlat; p.Bt = BtPQ; p.bias = zb;
      p.outb = Prc; p.ob_stride = 512;
      p.outS = Qc; p.oS_stride = 256; p.nsplit = 512;
      p.M = N_NODES; p.K = 320; p.Nw = 768; p.swzn = 6;
      gemm_k<5, 0, false, 8, false><<<gN8 * 6, 256, 0, stream>>>(p);
    }
    // fused edge GEMM1+GEMM2 -> el[:,64:128] (pre-LN new_edge)
    edge12_k<<<gE, 512, 0, stream>>>(el, rs, cs, Prc, BtWe, eb1c, Bte2, eb2c,
                                     el, N_EDGES);
    {  // msg GEMM (XCD-swizzled): relu(Qc[cs] + new_edge@Wm + b) -> msg [E,256]
      GemmP p{};
      p.E2 = el + 64; p.e2s = 128; p.row = rs; p.col = cs;
      p.Cc = Qc; p.cst = 256;
      p.Bt = BtWm; p.bias = mb1c;
      p.outb = msg; p.ob_stride = 256;
      p.M = N_EDGES; p.K = 64; p.Nw = 256; p.swzn = 2;
      gemm_k<0, 2, true, 8, false><<<gE8 * 2, 256, 0, stream>>>(p);
    }
    ln_edge_k<<<N_EDGES / 4, 256, 0, stream>>>(lnegc, lnebc, el);
    // fused attention softmax + aggregation (contiguous sorted segments)
    agg_csr_k<<<(N_NODES + 3) / 4, 256, 0, stream>>>(msg, attvc, offcsr, agg);
    {  // node GEMM + fused residual LayerNorm: agg@nW1 + b; LN(x + .) -> nlat
      GemmP p{};
      p.Af = agg; p.Bt = Btn1; p.bias = nb1c;
      p.X = xc; p.of_stride = 160;          // residual input + its stride
      p.Cr = lnngc; p.Cc = lnnbc;           // gamma / beta
      p.outb = nlat; p.ob_stride = 160;
      p.M = N_NODES; p.K = 256; p.Nw = 160;
      gemm_k<4, 0, false, 10, true><<<dim3(1, gN), 256, 0, stream>>>(p);
    }
  }

  out_node_k<<<(N_NODES * 160 + 255) / 256, 256, 0, stream>>>(nlat, d_out, flag);
  out_edge_k<<<(N_EDGES * 64 + 255) / 256, 256, 0, stream>>>(el, perm, d_out, flag);
  (void)out_size;
}

// Round 11
// 1893.998 us; speedup vs baseline: 1.0447x; 1.0447x over previous
//
#include <hip/hip_runtime.h>
#include <stdint.h>

#define N_NODES 50000
#define N_EDGES 200000
#define SCAN_B 512

typedef __bf16 bf16_t;
typedef bf16_t bf16x8 __attribute__((ext_vector_type(8)));
typedef float f32x4 __attribute__((ext_vector_type(4)));

__device__ __forceinline__ float bf2f(ushort h) {
  union { unsigned int u; float f; } c; c.u = ((unsigned int)h) << 16; return c.f;
}
__device__ __forceinline__ ushort f2bf(float f) {
  union { float f; unsigned int u; } c; c.f = f;
  unsigned int r = (c.u >> 16) & 1u;
  c.u += 0x7fffu + r;
  return (ushort)(c.u >> 16);
}
__device__ __forceinline__ float wave_sum(float v) {
#pragma unroll
  for (int m = 32; m > 0; m >>= 1) v += __shfl_xor(v, m, 64);
  return v;
}

// ---------------- input dtype detection + canonicalization ----------------
__global__ void detect_k(const ushort* x, unsigned int* flag) {
  int i = blockIdx.x * 256 + threadIdx.x;
  unsigned int cnt = 0;
  for (int j = i; j < 1000000; j += 64 * 256) {
    ushort v = x[j];
    if (((v & 0x7F80u) == 0x7F80u) && (v & 0x7Fu)) cnt++;
  }
  if (cnt) atomicAdd(flag, cnt);
}

__global__ void cvt_in_k(const void* src, ushort* dst, int n, const unsigned int* flag) {
  int i = blockIdx.x * 256 + threadIdx.x;
  if (i >= n) return;
  if (*flag >= 2) dst[i] = f2bf(((const float*)src)[i]);
  else            dst[i] = ((const ushort*)src)[i];
}

// permuted edge_attr convert: dst[e*8+j] = cvt(src[perm[e]*8+j])
__global__ void cvt_eattr_k(const void* src, const int* perm, ushort* dst,
                            const unsigned int* flag) {
  int i = blockIdx.x * 256 + threadIdx.x;
  if (i >= N_EDGES * 8) return;
  int e = i >> 3, j = i & 7;
  size_t o = (size_t)perm[e] * 8 + j;
  if (*flag >= 2) dst[i] = f2bf(((const float*)src)[o]);
  else            dst[i] = ((const ushort*)src)[o];
}

// Bt[n*Kpad + k] = W[(k0+k)*Wstride + n], zero-padded for k >= Ksrc
__global__ void transpose2_k(const void* W, ushort* Bt, int k0, int Ksrc, int Kpad,
                             int Wstride, const unsigned int* flag) {
  int k = blockIdx.x * 256 + threadIdx.x;
  int n = blockIdx.y;
  if (k >= Kpad) return;
  ushort v = 0;
  if (k < Ksrc) {
    if (*flag >= 2) v = f2bf(((const float*)W)[(size_t)(k0 + k) * Wstride + n]);
    else            v = ((const ushort*)W)[(size_t)(k0 + k) * Wstride + n];
  }
  Bt[(size_t)n * Kpad + k] = v;
}

// ---------------- CSR build (edge_row fixed across iterations) ----------------
__global__ void hist_k(const int* row, int* deg) {
  int e = blockIdx.x * 256 + threadIdx.x;
  if (e < N_EDGES) atomicAdd(&deg[row[e]], 1);
}
__global__ void scan_blk_k(const int* deg, int* off, int* bsum, int n) {
  __shared__ int s[SCAN_B];
  int i = blockIdx.x * SCAN_B + threadIdx.x;
  int v = (i < n) ? deg[i] : 0;
  s[threadIdx.x] = v;
  __syncthreads();
  for (int o = 1; o < SCAN_B; o <<= 1) {
    int t = (threadIdx.x >= o) ? s[threadIdx.x - o] : 0;
    __syncthreads();
    s[threadIdx.x] += t;
    __syncthreads();
  }
  if (i < n) off[i] = s[threadIdx.x] - v;  // exclusive (block-local)
  if (threadIdx.x == SCAN_B - 1) bsum[blockIdx.x] = s[SCAN_B - 1];
}
__global__ void scan_top_k(int* bsum, int nb) {  // single block, 128 threads
  __shared__ int s[128];
  int v = (threadIdx.x < nb) ? bsum[threadIdx.x] : 0;
  s[threadIdx.x] = v;
  __syncthreads();
  for (int o = 1; o < 128; o <<= 1) {
    int t = (threadIdx.x >= o) ? s[threadIdx.x - o] : 0;
    __syncthreads();
    s[threadIdx.x] += t;
    __syncthreads();
  }
  if (threadIdx.x < nb) bsum[threadIdx.x] = s[threadIdx.x] - v;  // exclusive
}
__global__ void scan_add_k(int* off, const int* bsum, int n) {
  int i = blockIdx.x * 256 + threadIdx.x;
  if (i < n) off[i] += bsum[i >> 9];
  if (i == 0) off[n] = N_EDGES;
}
__global__ void fill_k(const int* row, const int* off, int* cur, int* perm) {
  int e = blockIdx.x * 256 + threadIdx.x;
  if (e >= N_EDGES) return;
  int r = row[e];
  int p = off[r] + atomicAdd(&cur[r], 1);
  perm[p] = e;
}
__global__ void gather_rc_k(const int* row, const int* col, const int* perm,
                            int* rs, int* cs) {
  int e = blockIdx.x * 256 + threadIdx.x;
  if (e >= N_EDGES) return;
  int o = perm[e];
  rs[e] = row[o];
  cs[e] = col[o];
}

// ---------------- GEMM ----------------
// Grid: (n_blocks, m_blocks) — n in x (fast).
// A modes: 0 strided bf16 | 4 f32 | 5 [x|nlat] | 7 x pad | 8 eattr pad
// CI: 0 zeros | 1 Cr[row]+Cc[col] | 2 Cc[col]   (direct scalar gather)
// LNN: MODE-4-only fused residual+LayerNorm epilogue -> bf16 outb
struct GemmP {
  const ushort* X;
  const ushort* L;
  const ushort* E2;
  const float*  Af;
  const int* row;
  const int* col;
  const ushort* Bt;    // [Nw][K] transposed weight
  const ushort* bias;  // [Nw] bf16
  const ushort* Cr;    // CI: row-side partials | LNN: ln gamma
  const ushort* Cc;    // CI: col-side partials | LNN: ln beta
  long cst;
  ushort* outb;  long ob_stride;
  ushort* outb2; long ob2_stride;
  ushort* outS;  long oS_stride;   // column-split secondary dest
  int nsplit;                       // cols >= nsplit go to outS
  float*  outf;  long of_stride;    // LNN: stride of p.X residual
  long e2s;
  int M, K, Nw;
};

template <int MODE>
__device__ __forceinline__ uint4 load_a8(const GemmP& p, int e, int kg) {
  if (MODE == 0) {
    return *(const uint4*)(p.E2 + (size_t)e * p.e2s + kg);
  } else if (MODE == 5) {
    if (kg < 160) return *(const uint4*)(p.X + (size_t)e * 160 + kg);
    return *(const uint4*)(p.L + (size_t)e * 160 + (kg - 160));
  } else if (MODE == 7) {
    if (kg < 160) return *(const uint4*)(p.X + (size_t)e * 160 + kg);
    uint4 z; z.x = z.y = z.z = z.w = 0u; return z;
  } else if (MODE == 8) {
    if (kg < 8) return *(const uint4*)(p.E2 + (size_t)e * 8);
    uint4 z; z.x = z.y = z.z = z.w = 0u; return z;
  } else {  // MODE 4: f32 source
    const float* s = p.Af + (size_t)e * p.K + kg;
    f32x4 f0 = *(const f32x4*)s;
    f32x4 f1 = *(const f32x4*)(s + 4);
    union { ushort r[8]; uint4 u; } o;
    o.r[0] = f2bf(f0[0]); o.r[1] = f2bf(f0[1]); o.r[2] = f2bf(f0[2]); o.r[3] = f2bf(f0[3]);
    o.r[4] = f2bf(f1[0]); o.r[5] = f2bf(f1[1]); o.r[6] = f2bf(f1[2]); o.r[7] = f2bf(f1[3]);
    return o.u;
  }
}

// BM=128, BK=64, BN=NT*16. Register-prefetch pipeline; LDS-staged epilogue;
// direct scalar CI gather (measured faster than LDS-staged variants).
template <int MODE, int CI, bool RELU, int NT, bool LNN>
__global__ __launch_bounds__(256) void gemm_k(GemmP p) {
  constexpr int BR = NT / 2;
  constexpr int NTC = NT * 16;
  constexpr int CIP = NTC + 8;  // padded LDS stride (16B-aligned rows)
  __shared__ __align__(16) ushort smem[9216 + 1152 * NT];
  ushort* Asm = smem;
  ushort* Bsm = smem + 9216;
  const int t = threadIdx.x;
  const int w = t >> 6;
  const int l = t & 63;
  const int m0 = blockIdx.y * 128;   // m from y (slow axis)
  const int n0 = blockIdx.x * NTC;   // n from x (fast axis)

  // A staging: 2 threads/row, each 64B (4x16B) contiguous
  const int srow = t >> 1;
  const int sph = (t & 1) << 5;
  int e = m0 + srow;
  if (e >= p.M) e = p.M - 1;

  // B staging: flat chunk id -> (row, k8)
  int bn_[BR], bk_[BR];
#pragma unroll
  for (int j = 0; j < BR; j++) {
    int cid = j * 256 + t;
    bn_[j] = cid >> 3;
    bk_[j] = (cid & 7) << 3;
  }

  const int mq = l & 15;
  const int qd = l >> 4;

  uint4 ar[4];
  uint4 br[BR];
  auto load_tile = [&](int k0) {
#pragma unroll
    for (int j = 0; j < 4; j++)
      ar[j] = load_a8<MODE>(p, e, k0 + sph + j * 8);
#pragma unroll
    for (int j = 0; j < BR; j++)
      br[j] = *(const uint4*)(p.Bt + (size_t)(n0 + bn_[j]) * p.K + k0 + bk_[j]);
  };

  load_tile(0);

  f32x4 acc[2][NT] = {};
  if (CI) {
    // direct per-lane scalar gather (overlaps with the A/B prefetch above)
#pragma unroll
    for (int mt = 0; mt < 2; mt++) {
#pragma unroll
      for (int i = 0; i < 4; i++) {
        int r = m0 + w * 32 + mt * 16 + qd * 4 + i;
        if (r >= p.M) r = p.M - 1;
        const ushort* pc = p.Cc + (size_t)p.col[r] * p.cst + n0 + mq;
        const ushort* pr = nullptr;
        if (CI == 1) pr = p.Cr + (size_t)p.row[r] * p.cst + n0 + mq;
#pragma unroll
        for (int nt = 0; nt < NT; nt++) {
          float v = bf2f(pc[nt * 16]);
          if (CI == 1) v += bf2f(pr[nt * 16]);
          acc[mt][nt][i] = v;
        }
      }
    }
  }

  const int kiters = p.K >> 6;
  for (int kt = 0; kt < kiters; kt++) {
    __syncthreads();
#pragma unroll
    for (int j = 0; j < 4; j++)
      *(uint4*)&Asm[srow * 72 + sph + j * 8] = ar[j];
#pragma unroll
    for (int j = 0; j < BR; j++)
      *(uint4*)&Bsm[bn_[j] * 72 + bk_[j]] = br[j];
    if (kt + 1 < kiters) load_tile((kt + 1) << 6);
    __syncthreads();
#pragma unroll
    for (int ph = 0; ph < 2; ph++) {
      uint4 ra0 = *(const uint4*)&Asm[(w * 32 + mq) * 72 + ph * 32 + qd * 8];
      uint4 ra1 = *(const uint4*)&Asm[(w * 32 + 16 + mq) * 72 + ph * 32 + qd * 8];
      bf16x8 af0 = __builtin_bit_cast(bf16x8, ra0);
      bf16x8 af1 = __builtin_bit_cast(bf16x8, ra1);
#pragma unroll
      for (int nt = 0; nt < NT; nt++) {
        uint4 rb = *(const uint4*)&Bsm[(nt * 16 + mq) * 72 + ph * 32 + qd * 8];
        bf16x8 bfv = __builtin_bit_cast(bf16x8, rb);
        acc[0][nt] = __builtin_amdgcn_mfma_f32_16x16x32_bf16(af0, bfv, acc[0][nt], 0, 0, 0);
        acc[1][nt] = __builtin_amdgcn_mfma_f32_16x16x32_bf16(af1, bfv, acc[1][nt], 0, 0, 0);
      }
    }
  }

  if (MODE == 4) {
    if (LNN) {
      // fused: nn = acc + bias; v = x + nn; LN over 160 cols; -> outb bf16
#pragma unroll
      for (int mt = 0; mt < 2; mt++) {
#pragma unroll
        for (int i = 0; i < 4; i++) {
          int r = m0 + w * 32 + mt * 16 + qd * 4 + i;
          int rc = (r < p.M) ? r : p.M - 1;
          float vals[NT];
          float s = 0.0f;
#pragma unroll
          for (int nt = 0; nt < NT; nt++) {
            int c = n0 + nt * 16 + mq;
            float v = acc[mt][nt][i] + bf2f(p.bias[c]) +
                      bf2f(p.X[(size_t)rc * p.of_stride + c]);
            vals[nt] = v; s += v;
          }
#pragma unroll
          for (int m = 1; m <= 8; m <<= 1) s += __shfl_xor(s, m, 64);
          float mu = s * (1.0f / 160.0f);
          float ss = 0.0f;
#pragma unroll
          for (int nt = 0; nt < NT; nt++) { float d = vals[nt] - mu; ss += d * d; }
#pragma unroll
          for (int m = 1; m <= 8; m <<= 1) ss += __shfl_xor(ss, m, 64);
          float inv = rsqrtf(ss * (1.0f / 160.0f) + 1e-5f);
          if (r < p.M) {
#pragma unroll
            for (int nt = 0; nt < NT; nt++) {
              int c = n0 + nt * 16 + mq;
              float o = (vals[nt] - mu) * inv * bf2f(p.Cr[c]) + bf2f(p.Cc[c]);
              p.outb[(size_t)r * p.ob_stride + c] = f2bf(o);
            }
          }
        }
      }
    } else {
#pragma unroll
      for (int mt = 0; mt < 2; mt++) {
#pragma unroll
        for (int nt = 0; nt < NT; nt++) {
          int c = n0 + nt * 16 + mq;
          float bv = bf2f(p.bias[c]);
#pragma unroll
          for (int i = 0; i < 4; i++) {
            int r = m0 + w * 32 + mt * 16 + qd * 4 + i;
            if (r >= p.M) continue;
            float v = acc[mt][nt][i] + bv;
            if (RELU) v = fmaxf(v, 0.0f);
            p.outf[(size_t)r * p.of_stride + c] = v;
          }
        }
      }
    }
  } else {
    // bf16 output: stage per-wave 32xNTC tile in LDS (pad CIP), coalesced stores
    ushort* dst = p.outb;
    long dstr = p.ob_stride;
    int nb0 = n0;
    if (p.outS && n0 >= p.nsplit) { dst = p.outS; dstr = p.oS_stride; nb0 = n0 - p.nsplit; }
    __syncthreads();  // Asm/Bsm dead
    ushort* S = smem + w * (32 * CIP);
#pragma unroll
    for (int mt = 0; mt < 2; mt++) {
#pragma unroll
      for (int nt = 0; nt < NT; nt++) {
        float bv = bf2f(p.bias[n0 + nt * 16 + mq]);
#pragma unroll
        for (int i = 0; i < 4; i++) {
          float v = acc[mt][nt][i] + bv;
          if (RELU) v = fmaxf(v, 0.0f);
          S[(mt * 16 + qd * 4 + i) * CIP + nt * 16 + mq] = f2bf(v);
        }
      }
    }
    __syncthreads();
#pragma unroll
    for (int j = 0; j < NT; j++) {
      int flat = (j * 64 + l) * 8;
      int lr = flat / NTC, cc = flat % NTC;
      int r = m0 + w * 32 + lr;
      if (r < p.M) {
        uint4 v = *(const uint4*)&S[lr * CIP + cc];
        *(uint4*)(dst + (size_t)r * dstr + nb0 + cc) = v;
        if (p.outb2) *(uint4*)(p.outb2 + (size_t)r * p.ob2_stride + n0 + cc) = v;
      }
    }
  }
}

// ---------------- fused edge GEMM1+GEMM2+msg ----------------
// stage1: hm = relu(Pr[rs]+Pc[cs] + el@We + eb1)      [128x256] (LDS only)
// stage2: ne = hm @ W2 + eb2 -> el[:,64:128]           [128x64] (pre-LN)
// stage3: msg = relu(Qc[cs] + ne @ Wm + mb1) -> msg    [128x256]
// 512 threads = 8 waves x 16 rows each. All bf16 roundings identical to the
// unfused path (f2bf at each stage boundary).
__global__ __launch_bounds__(512) void edge123_k(
    const ushort* el, const int* rs, const int* cs, const ushort* Prc,
    const ushort* Qc, const ushort* BtWe, const ushort* eb1,
    const ushort* Bte2, const ushort* eb2, const ushort* BtWm,
    const ushort* mb1, ushort* elw, ushort* msg, int M) {
  __shared__ __align__(16) ushort smem[32768];  // 64 KB
  ushort* Asm = smem;           // 128*72 = 9216
  ushort* Bsm = smem + 9216;    // 256*72 = 18432 (ends 27648)
  const int t = threadIdx.x;    // 0..511
  const int w = t >> 6;         // 0..7
  const int l = t & 63;
  const int m0 = blockIdx.x * 128;
  const int mq = l & 15;
  const int qd = l >> 4;

  // A staging: 4 threads/row, 2x16B each
  const int arow = t >> 2;           // 0..127
  const int aph = (t & 3) << 4;      // 0/16/32/48
  int ea = m0 + arow;
  if (ea >= M) ea = M - 1;
  // B staging: 256 rows x 8 k-chunks = 2048 chunks / 512 thr = 4
  int bn_[4], bk_[4];
#pragma unroll
  for (int j = 0; j < 4; j++) {
    int cid = j * 512 + t;
    bn_[j] = cid >> 3;
    bk_[j] = (cid & 7) << 3;
  }

  uint4 ar[2], br[4];
  auto load_tile = [&](int k0) {
#pragma unroll
    for (int j = 0; j < 2; j++)
      ar[j] = *(const uint4*)(el + (size_t)ea * 128 + k0 + aph + j * 8);
#pragma unroll
    for (int j = 0; j < 4; j++)
      br[j] = *(const uint4*)(BtWe + (size_t)bn_[j] * 128 + k0 + bk_[j]);
  };
  load_tile(0);

  // stage-1 CI gather: rows r = m0 + w*16 + qd*4 + i; cols nt*16+mq
  f32x4 acc[16] = {};
#pragma unroll
  for (int i = 0; i < 4; i++) {
    int r = m0 + w * 16 + qd * 4 + i;
    if (r >= M) r = M - 1;
    const ushort* pc = Prc + (size_t)cs[r] * 512 + 256 + mq;
    const ushort* pr = Prc + (size_t)rs[r] * 512 + mq;
#pragma unroll
    for (int nt = 0; nt < 16; nt++)
      acc[nt][i] = bf2f(pc[nt * 16]) + bf2f(pr[nt * 16]);
  }

  // K-loop (K=128, 2 tiles)
#pragma unroll
  for (int kt = 0; kt < 2; kt++) {
    __syncthreads();
#pragma unroll
    for (int j = 0; j < 2; j++)
      *(uint4*)&Asm[arow * 72 + aph + j * 8] = ar[j];
#pragma unroll
    for (int j = 0; j < 4; j++)
      *(uint4*)&Bsm[bn_[j] * 72 + bk_[j]] = br[j];
    if (kt == 0) load_tile(64);
    __syncthreads();
#pragma unroll
    for (int ph = 0; ph < 2; ph++) {
      uint4 ra = *(const uint4*)&Asm[(w * 16 + mq) * 72 + ph * 32 + qd * 8];
      bf16x8 af = __builtin_bit_cast(bf16x8, ra);
#pragma unroll
      for (int nt = 0; nt < 16; nt++) {
        uint4 rb = *(const uint4*)&Bsm[(nt * 16 + mq) * 72 + ph * 32 + qd * 8];
        bf16x8 bfv = __builtin_bit_cast(bf16x8, rb);
        acc[nt] = __builtin_amdgcn_mfma_f32_16x16x32_bf16(af, bfv, acc[nt], 0, 0, 0);
      }
    }
  }

  // stage-1 epilogue -> wave-private LDS tile S (16x256, XOR-swizzled row&15)
  __syncthreads();  // staging dead
  ushort* S = smem + w * 4096;  // 16*256, disjoint per wave
#pragma unroll
  for (int nt = 0; nt < 16; nt++) {
    float bv = bf2f(eb1[nt * 16 + mq]);
#pragma unroll
    for (int i = 0; i < 4; i++) {
      int row = qd * 4 + i;
      float v = fmaxf(acc[nt][i] + bv, 0.0f);
      S[row * 256 + ((nt * 16 + mq) ^ ((row & 15) << 3))] = f2bf(v);
    }
  }

  // stage-3 CI gather (issue early; acc dead -> acc3 reuses registers)
  f32x4 acc3[16];
#pragma unroll
  for (int i = 0; i < 4; i++) {
    int r = m0 + w * 16 + qd * 4 + i;
    if (r >= M) r = M - 1;
    const ushort* pq = Qc + (size_t)cs[r] * 256 + mq;
#pragma unroll
    for (int nt = 0; nt < 16; nt++)
      acc3[nt][i] = bf2f(pq[nt * 16]);
  }
  __syncthreads();

  // stage-2: ne[16x64] = hm[16x256] @ W2[256x64]
  f32x4 acc2[4] = {};
#pragma unroll
  for (int ks = 0; ks < 8; ks++) {
    uint4 ra2 = *(const uint4*)&S[mq * 256 + ((ks * 32 + qd * 8) ^ ((mq & 15) << 3))];
    bf16x8 af2 = __builtin_bit_cast(bf16x8, ra2);
#pragma unroll
    for (int nt2 = 0; nt2 < 4; nt2++) {
      uint4 rb2 = *(const uint4*)(Bte2 + (size_t)(nt2 * 16 + mq) * 256 + ks * 32 + qd * 8);
      bf16x8 bf2v = __builtin_bit_cast(bf16x8, rb2);
      acc2[nt2] = __builtin_amdgcn_mfma_f32_16x16x32_bf16(af2, bf2v, acc2[nt2], 0, 0, 0);
    }
  }
  __syncthreads();  // all stage-2 reads of S done

  // write ne (pre-LN, bf16) into Sne (16x64 per wave, swizzled row&7)
  ushort* Sne = smem + w * 1024;
#pragma unroll
  for (int nt2 = 0; nt2 < 4; nt2++) {
    float bv2 = bf2f(eb2[nt2 * 16 + mq]);
#pragma unroll
    for (int i = 0; i < 4; i++) {
      int row = qd * 4 + i;
      Sne[row * 64 + ((nt2 * 16 + mq) ^ ((row & 7) << 3))] = f2bf(acc2[nt2][i] + bv2);
    }
  }
  __syncthreads();

  // el[:,64:128] write from Sne (coalesced)
  {
    int row = l >> 2;
    int r = m0 + w * 16 + row;
#pragma unroll
    for (int h = 0; h < 2; h++) {
      int cbase = (l & 3) * 16 + h * 8;
      if (r < M)
        *(uint4*)(elw + (size_t)r * 128 + 64 + cbase) =
            *(const uint4*)&Sne[row * 64 + (cbase ^ ((row & 7) << 3))];
    }
  }

  // stage-3: msg[16x256] = relu(Qc + ne[16x64] @ Wm[64x256] + mb1)
#pragma unroll
  for (int ph = 0; ph < 2; ph++) {
    uint4 ra3 = *(const uint4*)&Sne[mq * 64 + ((ph * 32 + qd * 8) ^ ((mq & 7) << 3))];
    bf16x8 af3 = __builtin_bit_cast(bf16x8, ra3);
#pragma unroll
    for (int nt = 0; nt < 16; nt++) {
      uint4 rb3 = *(const uint4*)(BtWm + (size_t)(nt * 16 + mq) * 64 + ph * 32 + qd * 8);
      bf16x8 bf3v = __builtin_bit_cast(bf16x8, rb3);
      acc3[nt] = __builtin_amdgcn_mfma_f32_16x16x32_bf16(af3, bf3v, acc3[nt], 0, 0, 0);
    }
  }
  __syncthreads();  // Sne reads done; reuse S region for msg restage

  // stage-3 epilogue: restage swizzled, then coalesced uint4 stores
#pragma unroll
  for (int nt = 0; nt < 16; nt++) {
    float bv3 = bf2f(mb1[nt * 16 + mq]);
#pragma unroll
    for (int i = 0; i < 4; i++) {
      int row = qd * 4 + i;
      float v = fmaxf(acc3[nt][i] + bv3, 0.0f);
      S[row * 256 + ((nt * 16 + mq) ^ ((row & 15) << 3))] = f2bf(v);
    }
  }
  __syncthreads();
#pragma unroll
  for (int j = 0; j < 8; j++) {
    int flat = (j * 64 + l) * 8;
    int row = flat >> 8, col = flat & 255;
    int r = m0 + w * 16 + row;
    if (r < M) {
      uint4 v = *(const uint4*)&S[row * 256 + (col ^ ((row & 15) << 3))];
      *(uint4*)(msg + (size_t)r * 256 + col) = v;
    }
  }
}

// ---------------- small kernels ----------------
__global__ void copy_u4_k(const uint4* s, uint4* d, int n) {
  int i = blockIdx.x * 256 + threadIdx.x;
  if (i < n) d[i] = s[i];
}

// Fused attention + aggregation, one wave per node; msg is row-sorted so the
// segment [off[n], off[n+1]) is contiguous.
__global__ void agg_csr_k(const ushort* msg, const ushort* att, const int* off,
                          float* agg) {
  int n = blockIdx.x * 4 + (threadIdx.x >> 6);
  int l = threadIdx.x & 63;
  if (n >= N_NODES) return;
  const int s0 = off[n], s1 = off[n + 1];
  ushort4 av = *(const ushort4*)(att + l * 4);
  const float a0 = bf2f(av.x), a1 = bf2f(av.y), a2 = bf2f(av.z), a3 = bf2f(av.w);
  float maxl = -1e30f;
  for (int j = s0; j < s1; j++) {
    ushort4 m = *(const ushort4*)(msg + (size_t)j * 256 + l * 4);
    float d = bf2f(m.x) * a0 + bf2f(m.y) * a1 + bf2f(m.z) * a2 + bf2f(m.w) * a3;
    d = wave_sum(d);
    float lg = (d > 0.0f) ? d : 0.2f * d;
    maxl = fmaxf(maxl, lg);
  }
  float den = 0.0f;
  f32x4 acc = {0.0f, 0.0f, 0.0f, 0.0f};
  for (int j = s0; j < s1; j++) {
    ushort4 m = *(const ushort4*)(msg + (size_t)j * 256 + l * 4);
    float m0 = bf2f(m.x), m1 = bf2f(m.y), m2 = bf2f(m.z), m3 = bf2f(m.w);
    float d = m0 * a0 + m1 * a1 + m2 * a2 + m3 * a3;
    d = wave_sum(d);
    float lg = (d > 0.0f) ? d : 0.2f * d;
    float ex = __expf(lg - maxl);
    den += ex;
    acc[0] += ex * m0; acc[1] += ex * m1; acc[2] += ex * m2; acc[3] += ex * m3;
  }
  float inv = 1.0f / (den + 1e-16f);
  f32x4 o = {acc[0] * inv, acc[1] * inv, acc[2] * inv, acc[3] * inv};
  *(f32x4*)(agg + (size_t)n * 256 + l * 4) = o;
}

__global__ void ln_edge_k(const ushort* g, const ushort* b, ushort* el) {
  int e = blockIdx.x * 4 + (threadIdx.x >> 6);
  int l = threadIdx.x & 63;
  if (e >= N_EDGES) return;
  float v = bf2f(el[(size_t)e * 128 + l]) + bf2f(el[(size_t)e * 128 + 64 + l]);
  float mu = wave_sum(v) * (1.0f / 64.0f);
  float d = v - mu;
  float var = wave_sum(d * d) * (1.0f / 64.0f);
  float inv = rsqrtf(var + 1e-5f);
  el[(size_t)e * 128 + 64 + l] = f2bf(d * inv * bf2f(g[l]) + bf2f(b[l]));
}

__global__ void out_node_k(const ushort* nlat, void* out, const unsigned int* flag) {
  int i = blockIdx.x * 256 + threadIdx.x;
  if (i >= N_NODES * 160) return;
  if (*flag >= 2) ((float*)out)[i] = bf2f(nlat[i]);
  else            ((ushort*)out)[i] = nlat[i];
}
// scatter sorted el back to original edge order via perm
__global__ void out_edge_k(const ushort* el, const int* perm, void* out,
                           const unsigned int* flag) {
  int i = blockIdx.x * 256 + threadIdx.x;
  if (i >= N_EDGES * 64) return;
  int e = i >> 6, c = i & 63;
  ushort v = el[(size_t)e * 128 + 64 + c];
  size_t o = (size_t)N_NODES * 160 + (size_t)perm[e] * 64 + c;
  if (*flag >= 2) ((float*)out)[o] = bf2f(v);
  else            ((ushort*)out)[o] = v;
}

// ---------------- host ----------------
extern "C" void kernel_launch(void* const* d_in, const int* in_sizes, int n_in,
                              void* d_out, int out_size, void* d_ws, size_t ws_size,
                              hipStream_t stream) {
  const void* x_r     = d_in[0];
  const void* eattr_r = d_in[1];
  const void* encW1   = d_in[2];
  const void* encb1_r = d_in[3];
  const void* encW2   = d_in[4];
  const void* encb2_r = d_in[5];
  const void* eW1     = d_in[6];
  const void* eb1_r   = d_in[7];
  const void* eW2     = d_in[8];
  const void* eb2_r   = d_in[9];
  const void* mW1     = d_in[10];
  const void* mb1_r   = d_in[11];
  const void* attv_r  = d_in[12];
  const void* nW1     = d_in[13];
  const void* nb1_r   = d_in[14];
  const void* lnng_r  = d_in[15];
  const void* lnnb_r  = d_in[16];
  const void* lneg_r  = d_in[17];
  const void* lneb_r  = d_in[18];
  const int* erow = (const int*)d_in[19];
  const int* ecol = (const int*)d_in[20];
  (void)in_sizes; (void)n_in;

  char* ws = (char*)d_ws;
  size_t off = 0;
  auto alloc = [&](size_t bytes) -> void* {
    void* p = ws + off;
    off = (off + bytes + 511) & ~(size_t)511;
    return p;
  };
  ushort* hm   = (ushort*)alloc((size_t)N_EDGES * 256 * 2);  // enc h / msg alias
  ushort* el   = (ushort*)alloc((size_t)N_EDGES * 128 * 2);
  float*  agg  = (float*)alloc((size_t)N_NODES * 256 * 4);   // eac/Penc/Prc alias
  ushort* xc   = (ushort*)alloc((size_t)N_NODES * 160 * 2);
  ushort* nlat = (ushort*)alloc((size_t)N_NODES * 160 * 2);
  ushort* Qc   = (ushort*)alloc((size_t)N_NODES * 256 * 2);  // nl @ mW1[0:320]
  int* degcur  = (int*)alloc((size_t)2 * N_NODES * 4);       // deg | cur
  int* offcsr  = (int*)alloc((size_t)(N_NODES + 1) * 4);
  int* perm    = (int*)alloc((size_t)N_EDGES * 4);
  int* rs      = (int*)alloc((size_t)N_EDGES * 4);
  int* cs      = (int*)alloc((size_t)N_EDGES * 4);
  int* bsum    = (int*)alloc((size_t)128 * 4);
  ushort* BtPe = (ushort*)alloc((size_t)256 * 192 * 2);  // [encW1_r|encW1_c]^T
  ushort* BtWenc = (ushort*)alloc((size_t)128 * 64 * 2); // encW1[320:328]^T (pad 64)
  ushort* BtE2 = (ushort*)alloc((size_t)64 * 128 * 2);
  ushort* BtPQ = (ushort*)alloc((size_t)768 * 320 * 2);  // [eW1_r|eW1_c|mW1q]^T
  ushort* BtWe = (ushort*)alloc((size_t)256 * 128 * 2);  // eW1[640:768]^T
  ushort* Bte2 = (ushort*)alloc((size_t)64 * 256 * 2);
  ushort* BtWm = (ushort*)alloc((size_t)256 * 64 * 2);   // mW1[320:384]^T
  ushort* Btn1 = (ushort*)alloc((size_t)160 * 256 * 2);
  ushort* pool = (ushort*)alloc((size_t)4096 * 2);
  unsigned int* flag = (unsigned int*)alloc(64);
  ushort* msg = hm;
  ushort* eac  = (ushort*)agg;                                    // [E,8] bf16
  ushort* Penc = (ushort*)((char*)agg + (size_t)N_EDGES * 8 * 2); // [N,256] bf16
  ushort* Prc  = (ushort*)agg;                                    // [N,512] bf16
  ushort* zb   = pool + 2048;                                     // zeros

  ushort* encb1c = pool;        ushort* encb2c = pool + 128;
  ushort* eb1c   = pool + 192;  ushort* eb2c   = pool + 448;
  ushort* mb1c   = pool + 512;  ushort* attvc  = pool + 768;
  ushort* nb1c   = pool + 1024; ushort* lnngc  = pool + 1184;
  ushort* lnnbc  = pool + 1344; ushort* lnegc  = pool + 1504;
  ushort* lnebc  = pool + 1568;

  if (off > ws_size) {
    hipMemsetAsync(d_out, 0, (size_t)out_size * 2, stream);
    return;
  }

  hipMemsetAsync(flag, 0, 64, stream);
  hipMemsetAsync(pool, 0, 4096 * 2, stream);
  hipMemsetAsync(degcur, 0, (size_t)2 * N_NODES * 4, stream);

  detect_k<<<64, 256, 0, stream>>>((const ushort*)x_r, flag);

  // CSR build (edge_row is iteration-invariant); all edge buffers stored sorted.
  {
    int* deg = degcur;
    int* cur = degcur + N_NODES;
    const int nb = (N_NODES + SCAN_B - 1) / SCAN_B;  // 98
    hist_k<<<(N_EDGES + 255) / 256, 256, 0, stream>>>(erow, deg);
    scan_blk_k<<<nb, SCAN_B, 0, stream>>>(deg, offcsr, bsum, N_NODES);
    scan_top_k<<<1, 128, 0, stream>>>(bsum, nb);
    scan_add_k<<<(N_NODES + 255) / 256, 256, 0, stream>>>(offcsr, bsum, N_NODES);
    fill_k<<<(N_EDGES + 255) / 256, 256, 0, stream>>>(erow, offcsr, cur, perm);
    gather_rc_k<<<(N_EDGES + 255) / 256, 256, 0, stream>>>(erow, ecol, perm, rs, cs);
  }

  cvt_in_k<<<(N_NODES * 160 + 255) / 256, 256, 0, stream>>>(x_r, xc, N_NODES * 160, flag);
  cvt_eattr_k<<<(N_EDGES * 8 + 255) / 256, 256, 0, stream>>>(eattr_r, perm, eac, flag);
  cvt_in_k<<<1, 256, 0, stream>>>(encb1_r, encb1c, 128, flag);
  cvt_in_k<<<1, 256, 0, stream>>>(encb2_r, encb2c, 64, flag);
  cvt_in_k<<<1, 256, 0, stream>>>(eb1_r, eb1c, 256, flag);
  cvt_in_k<<<1, 256, 0, stream>>>(eb2_r, eb2c, 64, flag);
  cvt_in_k<<<1, 256, 0, stream>>>(mb1_r, mb1c, 256, flag);
  cvt_in_k<<<1, 256, 0, stream>>>(attv_r, attvc, 256, flag);
  cvt_in_k<<<1, 256, 0, stream>>>(nb1_r, nb1c, 160, flag);
  cvt_in_k<<<1, 256, 0, stream>>>(lnng_r, lnngc, 160, flag);
  cvt_in_k<<<1, 256, 0, stream>>>(lnnb_r, lnnbc, 160, flag);
  cvt_in_k<<<1, 256, 0, stream>>>(lneg_r, lnegc, 64, flag);
  cvt_in_k<<<1, 256, 0, stream>>>(lneb_r, lnebc, 64, flag);

  // weight transposes (Bt[n][k] layout, K zero-padded to multiple of 64)
  transpose2_k<<<dim3(1, 128), 256, 0, stream>>>(encW1, BtPe,             0, 160, 192, 128, flag);
  transpose2_k<<<dim3(1, 128), 256, 0, stream>>>(encW1, BtPe + 128 * 192, 160, 160, 192, 128, flag);
  transpose2_k<<<dim3(1, 128), 256, 0, stream>>>(encW1, BtWenc,           320, 8, 64, 128, flag);
  transpose2_k<<<dim3(1, 64), 256, 0, stream>>>(encW2, BtE2, 0, 128, 128, 64, flag);
  transpose2_k<<<dim3(2, 256), 256, 0, stream>>>(eW1, BtPQ,             0, 320, 320, 256, flag);
  transpose2_k<<<dim3(2, 256), 256, 0, stream>>>(eW1, BtPQ + 256 * 320, 320, 320, 320, 256, flag);
  transpose2_k<<<dim3(2, 256), 256, 0, stream>>>(mW1, BtPQ + 512 * 320, 0, 320, 320, 256, flag);
  transpose2_k<<<dim3(1, 256), 256, 0, stream>>>(eW1, BtWe, 640, 128, 128, 256, flag);
  transpose2_k<<<dim3(1, 64), 256, 0, stream>>>(eW2, Bte2, 0, 256, 256, 64, flag);
  transpose2_k<<<dim3(1, 256), 256, 0, stream>>>(mW1, BtWm, 320, 64, 64, 256, flag);
  transpose2_k<<<dim3(1, 160), 256, 0, stream>>>(nW1, Btn1, 0, 256, 256, 160, flag);

  copy_u4_k<<<(N_NODES * 160 / 8 + 255) / 256, 256, 0, stream>>>(
      (const uint4*)xc, (uint4*)nlat, N_NODES * 160 / 8);

  const int gE = (N_EDGES + 127) / 128;  // 1563
  const int gN = (N_NODES + 127) / 128;  // 391

  {  // enc pre-GEMM: Penc = x @ [encW1_r | encW1_c]   [N,256]
    GemmP p{};
    p.X = xc; p.Bt = BtPe; p.bias = zb;
    p.outb = Penc; p.ob_stride = 256;
    p.M = N_NODES; p.K = 192; p.Nw = 256;
    gemm_k<7, 0, false, 8, false><<<dim3(2, gN), 256, 0, stream>>>(p);
  }
  {  // enc edge GEMM: relu(Penc_r[rs]+Penc_c[cs] + eattr@Wenc + b) -> hm [E,128]
    GemmP p{};
    p.E2 = eac; p.row = rs; p.col = cs;
    p.Cr = Penc; p.Cc = Penc + 128; p.cst = 256;
    p.Bt = BtWenc; p.bias = encb1c;
    p.outb = hm; p.ob_stride = 128;
    p.M = N_EDGES; p.K = 64; p.Nw = 128;
    gemm_k<8, 1, true, 8, false><<<dim3(1, gE), 256, 0, stream>>>(p);
  }
  {  // encoder GEMM2: hm @ [128,64] -> el[:,0:64] and el[:,64:128]
    GemmP p{};
    p.E2 = hm; p.e2s = 128; p.Bt = BtE2; p.bias = encb2c;
    p.outb = el; p.ob_stride = 128;
    p.outb2 = el + 64; p.ob2_stride = 128;
    p.M = N_EDGES; p.K = 128; p.Nw = 64;
    gemm_k<0, 0, false, 4, false><<<dim3(1, gE), 256, 0, stream>>>(p);
  }

  for (int it = 0; it < 3; it++) {
    {  // merged node pre-GEMM: [x|nlat] @ [eW1_r|eW1_c|mW1q] -> Prc + Qc
      GemmP p{};
      p.X = xc; p.L = nlat; p.Bt = BtPQ; p.bias = zb;
      p.outb = Prc; p.ob_stride = 512;
      p.outS = Qc; p.oS_stride = 256; p.nsplit = 512;
      p.M = N_NODES; p.K = 320; p.Nw = 768;
      gemm_k<5, 0, false, 8, false><<<dim3(6, gN), 256, 0, stream>>>(p);
    }
    // fused edge GEMM1+GEMM2+msg -> el[:,64:128] (pre-LN) and msg [E,256]
    edge123_k<<<gE, 512, 0, stream>>>(el, rs, cs, Prc, Qc, BtWe, eb1c,
                                      Bte2, eb2c, BtWm, mb1c, el, msg, N_EDGES);
    ln_edge_k<<<N_EDGES / 4, 256, 0, stream>>>(lnegc, lnebc, el);
    // fused attention softmax + aggregation (contiguous sorted segments)
    agg_csr_k<<<(N_NODES + 3) / 4, 256, 0, stream>>>(msg, attvc, offcsr, agg);
    {  // node GEMM + fused residual LayerNorm: agg@nW1 + b; LN(x + .) -> nlat
      GemmP p{};
      p.Af = agg; p.Bt = Btn1; p.bias = nb1c;
      p.X = xc; p.of_stride = 160;          // residual input + its stride
      p.Cr = lnngc; p.Cc = lnnbc;           // gamma / beta
      p.outb = nlat; p.ob_stride = 160;
      p.M = N_NODES; p.K = 256; p.Nw = 160;
      gemm_k<4, 0, false, 10, true><<<dim3(1, gN), 256, 0, stream>>>(p);
    }
  }

  out_node_k<<<(N_NODES * 160 + 255) / 256, 256, 0, stream>>>(nlat, d_out, flag);
  out_edge_k<<<(N_EDGES * 64 + 255) / 256, 256, 0, stream>>>(el, perm, d_out, flag);
  (void)out_size;
}

// Round 12
// 1758.523 us; speedup vs baseline: 1.1252x; 1.0770x over previous
//
#include <hip/hip_runtime.h>
#include <stdint.h>

#define N_NODES 50000
#define N_EDGES 200000
#define SCAN_B 512

typedef __bf16 bf16_t;
typedef bf16_t bf16x8 __attribute__((ext_vector_type(8)));
typedef float f32x4 __attribute__((ext_vector_type(4)));

__device__ __forceinline__ float bf2f(ushort h) {
  union { unsigned int u; float f; } c; c.u = ((unsigned int)h) << 16; return c.f;
}
__device__ __forceinline__ ushort f2bf(float f) {
  union { float f; unsigned int u; } c; c.f = f;
  unsigned int r = (c.u >> 16) & 1u;
  c.u += 0x7fffu + r;
  return (ushort)(c.u >> 16);
}
__device__ __forceinline__ float wave_sum(float v) {
#pragma unroll
  for (int m = 32; m > 0; m >>= 1) v += __shfl_xor(v, m, 64);
  return v;
}

// ---------------- input dtype detection + canonicalization ----------------
__global__ void detect_k(const ushort* x, unsigned int* flag) {
  int i = blockIdx.x * 256 + threadIdx.x;
  unsigned int cnt = 0;
  for (int j = i; j < 1000000; j += 64 * 256) {
    ushort v = x[j];
    if (((v & 0x7F80u) == 0x7F80u) && (v & 0x7Fu)) cnt++;
  }
  if (cnt) atomicAdd(flag, cnt);
}

__global__ void cvt_in_k(const void* src, ushort* dst, int n, const unsigned int* flag) {
  int i = blockIdx.x * 256 + threadIdx.x;
  if (i >= n) return;
  if (*flag >= 2) dst[i] = f2bf(((const float*)src)[i]);
  else            dst[i] = ((const ushort*)src)[i];
}

// permuted edge_attr convert: dst[e*8+j] = cvt(src[perm[e]*8+j])
__global__ void cvt_eattr_k(const void* src, const int* perm, ushort* dst,
                            const unsigned int* flag) {
  int i = blockIdx.x * 256 + threadIdx.x;
  if (i >= N_EDGES * 8) return;
  int e = i >> 3, j = i & 7;
  size_t o = (size_t)perm[e] * 8 + j;
  if (*flag >= 2) dst[i] = f2bf(((const float*)src)[o]);
  else            dst[i] = ((const ushort*)src)[o];
}

// Bt[n*Kpad + k] = W[(k0+k)*Wstride + n], zero-padded for k >= Ksrc
__global__ void transpose2_k(const void* W, ushort* Bt, int k0, int Ksrc, int Kpad,
                             int Wstride, const unsigned int* flag) {
  int k = blockIdx.x * 256 + threadIdx.x;
  int n = blockIdx.y;
  if (k >= Kpad) return;
  ushort v = 0;
  if (k < Ksrc) {
    if (*flag >= 2) v = f2bf(((const float*)W)[(size_t)(k0 + k) * Wstride + n]);
    else            v = ((const ushort*)W)[(size_t)(k0 + k) * Wstride + n];
  }
  Bt[(size_t)n * Kpad + k] = v;
}

// ---------------- CSR build (edge_row fixed across iterations) ----------------
__global__ void hist_k(const int* row, int* deg) {
  int e = blockIdx.x * 256 + threadIdx.x;
  if (e < N_EDGES) atomicAdd(&deg[row[e]], 1);
}
__global__ void scan_blk_k(const int* deg, int* off, int* bsum, int n) {
  __shared__ int s[SCAN_B];
  int i = blockIdx.x * SCAN_B + threadIdx.x;
  int v = (i < n) ? deg[i] : 0;
  s[threadIdx.x] = v;
  __syncthreads();
  for (int o = 1; o < SCAN_B; o <<= 1) {
    int t = (threadIdx.x >= o) ? s[threadIdx.x - o] : 0;
    __syncthreads();
    s[threadIdx.x] += t;
    __syncthreads();
  }
  if (i < n) off[i] = s[threadIdx.x] - v;  // exclusive (block-local)
  if (threadIdx.x == SCAN_B - 1) bsum[blockIdx.x] = s[SCAN_B - 1];
}
__global__ void scan_top_k(int* bsum, int nb) {  // single block, 128 threads
  __shared__ int s[128];
  int v = (threadIdx.x < nb) ? bsum[threadIdx.x] : 0;
  s[threadIdx.x] = v;
  __syncthreads();
  for (int o = 1; o < 128; o <<= 1) {
    int t = (threadIdx.x >= o) ? s[threadIdx.x - o] : 0;
    __syncthreads();
    s[threadIdx.x] += t;
    __syncthreads();
  }
  if (threadIdx.x < nb) bsum[threadIdx.x] = s[threadIdx.x] - v;  // exclusive
}
__global__ void scan_add_k(int* off, const int* bsum, int n) {
  int i = blockIdx.x * 256 + threadIdx.x;
  if (i < n) off[i] += bsum[i >> 9];
  if (i == 0) off[n] = N_EDGES;
}
__global__ void fill_k(const int* row, const int* off, int* cur, int* perm) {
  int e = blockIdx.x * 256 + threadIdx.x;
  if (e >= N_EDGES) return;
  int r = row[e];
  int p = off[r] + atomicAdd(&cur[r], 1);
  perm[p] = e;
}
__global__ void gather_rc_k(const int* row, const int* col, const int* perm,
                            int* rs, int* cs) {
  int e = blockIdx.x * 256 + threadIdx.x;
  if (e >= N_EDGES) return;
  int o = perm[e];
  rs[e] = row[o];
  cs[e] = col[o];
}

// ---------------- GEMM ----------------
// Grid: (n_blocks, m_blocks) — n in x (fast).
// A modes: 0 strided bf16 | 4 f32 | 5 [x|nlat] | 7 x pad | 8 eattr pad
// CI: 0 zeros | 1 Cr[row]+Cc[col] | 2 Cc[col]   (direct scalar gather)
// LNN: MODE-4-only fused residual+LayerNorm epilogue -> bf16 outb
// BK: K-tile (64 default; 32 for latency-bound CI kernels -> lower LDS,
//     higher occupancy: 36.9KB/4blk -> 20.5KB/7blk per CU)
struct GemmP {
  const ushort* X;
  const ushort* L;
  const ushort* E2;
  const float*  Af;
  const int* row;
  const int* col;
  const ushort* Bt;    // [Nw][K] transposed weight
  const ushort* bias;  // [Nw] bf16
  const ushort* Cr;    // CI: row-side partials | LNN: ln gamma
  const ushort* Cc;    // CI: col-side partials | LNN: ln beta
  long cst;
  ushort* outb;  long ob_stride;
  ushort* outb2; long ob2_stride;
  ushort* outS;  long oS_stride;   // column-split secondary dest
  int nsplit;                       // cols >= nsplit go to outS
  float*  outf;  long of_stride;    // LNN: stride of p.X residual
  long e2s;
  int M, K, Nw;
};

template <int MODE>
__device__ __forceinline__ uint4 load_a8(const GemmP& p, int e, int kg) {
  if (MODE == 0) {
    return *(const uint4*)(p.E2 + (size_t)e * p.e2s + kg);
  } else if (MODE == 5) {
    if (kg < 160) return *(const uint4*)(p.X + (size_t)e * 160 + kg);
    return *(const uint4*)(p.L + (size_t)e * 160 + (kg - 160));
  } else if (MODE == 7) {
    if (kg < 160) return *(const uint4*)(p.X + (size_t)e * 160 + kg);
    uint4 z; z.x = z.y = z.z = z.w = 0u; return z;
  } else if (MODE == 8) {
    if (kg < 8) return *(const uint4*)(p.E2 + (size_t)e * 8);
    uint4 z; z.x = z.y = z.z = z.w = 0u; return z;
  } else {  // MODE 4: f32 source
    const float* s = p.Af + (size_t)e * p.K + kg;
    f32x4 f0 = *(const f32x4*)s;
    f32x4 f1 = *(const f32x4*)(s + 4);
    union { ushort r[8]; uint4 u; } o;
    o.r[0] = f2bf(f0[0]); o.r[1] = f2bf(f0[1]); o.r[2] = f2bf(f0[2]); o.r[3] = f2bf(f0[3]);
    o.r[4] = f2bf(f1[0]); o.r[5] = f2bf(f1[1]); o.r[6] = f2bf(f1[2]); o.r[7] = f2bf(f1[3]);
    return o.u;
  }
}

// BM=128, BKxNT*16 tiles. Register-prefetch pipeline; two-pass LDS epilogue;
// direct scalar CI gather (measured faster than LDS-staged variants).
template <int MODE, int CI, bool RELU, int NT, bool LNN, int BK>
__global__ __launch_bounds__(256) void gemm_k(GemmP p) {
  constexpr int NTC = NT * 16;
  constexpr int BKP = BK + 8;       // padded K stride
  constexpr int CIP = NTC + 8;      // padded epilogue stride
  constexpr int AR  = BK / 16;      // A uint4s per thread per tile
  constexpr int BR  = NT * BK / 128;// B uint4s per thread per tile
  constexpr int KC  = BK / 8;       // B k-chunks per row
  constexpr int SZ1 = (128 + NTC) * BKP;
  constexpr int SZ2 = 64 * CIP;     // 4 waves x 16 rows x CIP
  constexpr int SMEM = SZ1 > SZ2 ? SZ1 : SZ2;
  __shared__ __align__(16) ushort smem[SMEM];
  ushort* Asm = smem;
  ushort* Bsm = smem + 128 * BKP;
  const int t = threadIdx.x;
  const int w = t >> 6;
  const int l = t & 63;
  const int m0 = blockIdx.y * 128;   // m from y (slow axis)
  const int n0 = blockIdx.x * NTC;   // n from x (fast axis)

  // A staging: 2 threads/row, each BK/2 elems contiguous
  const int srow = t >> 1;
  const int sph = (t & 1) * (BK / 2);
  int e = m0 + srow;
  if (e >= p.M) e = p.M - 1;

  // B staging: flat chunk id -> (row, k8)
  int bn_[BR], bk_[BR];
#pragma unroll
  for (int j = 0; j < BR; j++) {
    int cid = j * 256 + t;
    bn_[j] = cid / KC;
    bk_[j] = (cid % KC) * 8;
  }

  const int mq = l & 15;
  const int qd = l >> 4;

  uint4 ar[AR];
  uint4 br[BR];
  auto load_tile = [&](int k0) {
#pragma unroll
    for (int j = 0; j < AR; j++)
      ar[j] = load_a8<MODE>(p, e, k0 + sph + j * 8);
#pragma unroll
    for (int j = 0; j < BR; j++)
      br[j] = *(const uint4*)(p.Bt + (size_t)(n0 + bn_[j]) * p.K + k0 + bk_[j]);
  };

  load_tile(0);

  f32x4 acc[2][NT] = {};
  if (CI) {
    // direct per-lane scalar gather (overlaps with the A/B prefetch above)
#pragma unroll
    for (int mt = 0; mt < 2; mt++) {
#pragma unroll
      for (int i = 0; i < 4; i++) {
        int r = m0 + w * 32 + mt * 16 + qd * 4 + i;
        if (r >= p.M) r = p.M - 1;
        const ushort* pc = p.Cc + (size_t)p.col[r] * p.cst + n0 + mq;
        const ushort* pr = nullptr;
        if (CI == 1) pr = p.Cr + (size_t)p.row[r] * p.cst + n0 + mq;
#pragma unroll
        for (int nt = 0; nt < NT; nt++) {
          float v = bf2f(pc[nt * 16]);
          if (CI == 1) v += bf2f(pr[nt * 16]);
          acc[mt][nt][i] = v;
        }
      }
    }
  }

  const int kiters = p.K / BK;
  for (int kt = 0; kt < kiters; kt++) {
    __syncthreads();
#pragma unroll
    for (int j = 0; j < AR; j++)
      *(uint4*)&Asm[srow * BKP + sph + j * 8] = ar[j];
#pragma unroll
    for (int j = 0; j < BR; j++)
      *(uint4*)&Bsm[bn_[j] * BKP + bk_[j]] = br[j];
    if (kt + 1 < kiters) load_tile((kt + 1) * BK);
    __syncthreads();
#pragma unroll
    for (int ph = 0; ph < BK / 32; ph++) {
      uint4 ra0 = *(const uint4*)&Asm[(w * 32 + mq) * BKP + ph * 32 + qd * 8];
      uint4 ra1 = *(const uint4*)&Asm[(w * 32 + 16 + mq) * BKP + ph * 32 + qd * 8];
      bf16x8 af0 = __builtin_bit_cast(bf16x8, ra0);
      bf16x8 af1 = __builtin_bit_cast(bf16x8, ra1);
#pragma unroll
      for (int nt = 0; nt < NT; nt++) {
        uint4 rb = *(const uint4*)&Bsm[(nt * 16 + mq) * BKP + ph * 32 + qd * 8];
        bf16x8 bfv = __builtin_bit_cast(bf16x8, rb);
        acc[0][nt] = __builtin_amdgcn_mfma_f32_16x16x32_bf16(af0, bfv, acc[0][nt], 0, 0, 0);
        acc[1][nt] = __builtin_amdgcn_mfma_f32_16x16x32_bf16(af1, bfv, acc[1][nt], 0, 0, 0);
      }
    }
  }

  if (MODE == 4) {
    if (LNN) {
      // fused: nn = acc + bias; v = x + nn; LN over 160 cols; -> outb bf16
#pragma unroll
      for (int mt = 0; mt < 2; mt++) {
#pragma unroll
        for (int i = 0; i < 4; i++) {
          int r = m0 + w * 32 + mt * 16 + qd * 4 + i;
          int rc = (r < p.M) ? r : p.M - 1;
          float vals[NT];
          float s = 0.0f;
#pragma unroll
          for (int nt = 0; nt < NT; nt++) {
            int c = n0 + nt * 16 + mq;
            float v = acc[mt][nt][i] + bf2f(p.bias[c]) +
                      bf2f(p.X[(size_t)rc * p.of_stride + c]);
            vals[nt] = v; s += v;
          }
#pragma unroll
          for (int m = 1; m <= 8; m <<= 1) s += __shfl_xor(s, m, 64);
          float mu = s * (1.0f / 160.0f);
          float ss = 0.0f;
#pragma unroll
          for (int nt = 0; nt < NT; nt++) { float d = vals[nt] - mu; ss += d * d; }
#pragma unroll
          for (int m = 1; m <= 8; m <<= 1) ss += __shfl_xor(ss, m, 64);
          float inv = rsqrtf(ss * (1.0f / 160.0f) + 1e-5f);
          if (r < p.M) {
#pragma unroll
            for (int nt = 0; nt < NT; nt++) {
              int c = n0 + nt * 16 + mq;
              float o = (vals[nt] - mu) * inv * bf2f(p.Cr[c]) + bf2f(p.Cc[c]);
              p.outb[(size_t)r * p.ob_stride + c] = f2bf(o);
            }
          }
        }
      }
    } else {
#pragma unroll
      for (int mt = 0; mt < 2; mt++) {
#pragma unroll
        for (int nt = 0; nt < NT; nt++) {
          int c = n0 + nt * 16 + mq;
          float bv = bf2f(p.bias[c]);
#pragma unroll
          for (int i = 0; i < 4; i++) {
            int r = m0 + w * 32 + mt * 16 + qd * 4 + i;
            if (r >= p.M) continue;
            float v = acc[mt][nt][i] + bv;
            if (RELU) v = fmaxf(v, 0.0f);
            p.outf[(size_t)r * p.of_stride + c] = v;
          }
        }
      }
    }
  } else {
    // bf16 output: two-pass per-wave 16xNTC LDS staging, coalesced uint4 stores
    ushort* dst = p.outb;
    long dstr = p.ob_stride;
    int nb0 = n0;
    if (p.outS && n0 >= p.nsplit) { dst = p.outS; dstr = p.oS_stride; nb0 = n0 - p.nsplit; }
    ushort* S = smem + w * (16 * CIP);
#pragma unroll
    for (int mt = 0; mt < 2; mt++) {
      __syncthreads();  // staging (mt=0) / prior reads (mt=1) dead
#pragma unroll
      for (int nt = 0; nt < NT; nt++) {
        float bv = bf2f(p.bias[n0 + nt * 16 + mq]);
#pragma unroll
        for (int i = 0; i < 4; i++) {
          float v = acc[mt][nt][i] + bv;
          if (RELU) v = fmaxf(v, 0.0f);
          S[(qd * 4 + i) * CIP + nt * 16 + mq] = f2bf(v);
        }
      }
      __syncthreads();
#pragma unroll
      for (int j = 0; j < NT / 2; j++) {
        int flat = (j * 64 + l) * 8;
        int lr = flat / NTC, cc = flat % NTC;
        int r = m0 + w * 32 + mt * 16 + lr;
        if (r < p.M) {
          uint4 v = *(const uint4*)&S[lr * CIP + cc];
          *(uint4*)(dst + (size_t)r * dstr + nb0 + cc) = v;
          if (p.outb2) *(uint4*)(p.outb2 + (size_t)r * p.ob2_stride + n0 + cc) = v;
        }
      }
    }
  }
}

// ---------------- small kernels ----------------
__global__ void copy_u4_k(const uint4* s, uint4* d, int n) {
  int i = blockIdx.x * 256 + threadIdx.x;
  if (i < n) d[i] = s[i];
}

// Fused attention + aggregation, one wave per node; msg is row-sorted so the
// segment [off[n], off[n+1]) is contiguous.
__global__ void agg_csr_k(const ushort* msg, const ushort* att, const int* off,
                          float* agg) {
  int n = blockIdx.x * 4 + (threadIdx.x >> 6);
  int l = threadIdx.x & 63;
  if (n >= N_NODES) return;
  const int s0 = off[n], s1 = off[n + 1];
  ushort4 av = *(const ushort4*)(att + l * 4);
  const float a0 = bf2f(av.x), a1 = bf2f(av.y), a2 = bf2f(av.z), a3 = bf2f(av.w);
  float maxl = -1e30f;
  for (int j = s0; j < s1; j++) {
    ushort4 m = *(const ushort4*)(msg + (size_t)j * 256 + l * 4);
    float d = bf2f(m.x) * a0 + bf2f(m.y) * a1 + bf2f(m.z) * a2 + bf2f(m.w) * a3;
    d = wave_sum(d);
    float lg = (d > 0.0f) ? d : 0.2f * d;
    maxl = fmaxf(maxl, lg);
  }
  float den = 0.0f;
  f32x4 acc = {0.0f, 0.0f, 0.0f, 0.0f};
  for (int j = s0; j < s1; j++) {
    ushort4 m = *(const ushort4*)(msg + (size_t)j * 256 + l * 4);
    float m0 = bf2f(m.x), m1 = bf2f(m.y), m2 = bf2f(m.z), m3 = bf2f(m.w);
    float d = m0 * a0 + m1 * a1 + m2 * a2 + m3 * a3;
    d = wave_sum(d);
    float lg = (d > 0.0f) ? d : 0.2f * d;
    float ex = __expf(lg - maxl);
    den += ex;
    acc[0] += ex * m0; acc[1] += ex * m1; acc[2] += ex * m2; acc[3] += ex * m3;
  }
  float inv = 1.0f / (den + 1e-16f);
  f32x4 o = {acc[0] * inv, acc[1] * inv, acc[2] * inv, acc[3] * inv};
  *(f32x4*)(agg + (size_t)n * 256 + l * 4) = o;
}

__global__ void ln_edge_k(const ushort* g, const ushort* b, ushort* el) {
  int e = blockIdx.x * 4 + (threadIdx.x >> 6);
  int l = threadIdx.x & 63;
  if (e >= N_EDGES) return;
  float v = bf2f(el[(size_t)e * 128 + l]) + bf2f(el[(size_t)e * 128 + 64 + l]);
  float mu = wave_sum(v) * (1.0f / 64.0f);
  float d = v - mu;
  float var = wave_sum(d * d) * (1.0f / 64.0f);
  float inv = rsqrtf(var + 1e-5f);
  el[(size_t)e * 128 + 64 + l] = f2bf(d * inv * bf2f(g[l]) + bf2f(b[l]));
}

__global__ void out_node_k(const ushort* nlat, void* out, const unsigned int* flag) {
  int i = blockIdx.x * 256 + threadIdx.x;
  if (i >= N_NODES * 160) return;
  if (*flag >= 2) ((float*)out)[i] = bf2f(nlat[i]);
  else            ((ushort*)out)[i] = nlat[i];
}
// scatter sorted el back to original edge order via perm
__global__ void out_edge_k(const ushort* el, const int* perm, void* out,
                           const unsigned int* flag) {
  int i = blockIdx.x * 256 + threadIdx.x;
  if (i >= N_EDGES * 64) return;
  int e = i >> 6, c = i & 63;
  ushort v = el[(size_t)e * 128 + 64 + c];
  size_t o = (size_t)N_NODES * 160 + (size_t)perm[e] * 64 + c;
  if (*flag >= 2) ((float*)out)[o] = bf2f(v);
  else            ((ushort*)out)[o] = v;
}

// ---------------- host ----------------
extern "C" void kernel_launch(void* const* d_in, const int* in_sizes, int n_in,
                              void* d_out, int out_size, void* d_ws, size_t ws_size,
                              hipStream_t stream) {
  const void* x_r     = d_in[0];
  const void* eattr_r = d_in[1];
  const void* encW1   = d_in[2];
  const void* encb1_r = d_in[3];
  const void* encW2   = d_in[4];
  const void* encb2_r = d_in[5];
  const void* eW1     = d_in[6];
  const void* eb1_r   = d_in[7];
  const void* eW2     = d_in[8];
  const void* eb2_r   = d_in[9];
  const void* mW1     = d_in[10];
  const void* mb1_r   = d_in[11];
  const void* attv_r  = d_in[12];
  const void* nW1     = d_in[13];
  const void* nb1_r   = d_in[14];
  const void* lnng_r  = d_in[15];
  const void* lnnb_r  = d_in[16];
  const void* lneg_r  = d_in[17];
  const void* lneb_r  = d_in[18];
  const int* erow = (const int*)d_in[19];
  const int* ecol = (const int*)d_in[20];
  (void)in_sizes; (void)n_in;

  char* ws = (char*)d_ws;
  size_t off = 0;
  auto alloc = [&](size_t bytes) -> void* {
    void* p = ws + off;
    off = (off + bytes + 511) & ~(size_t)511;
    return p;
  };
  ushort* hm   = (ushort*)alloc((size_t)N_EDGES * 256 * 2);  // enc h / msg alias
  ushort* el   = (ushort*)alloc((size_t)N_EDGES * 128 * 2);
  float*  agg  = (float*)alloc((size_t)N_NODES * 256 * 4);   // eac/Penc/Prc alias
  ushort* xc   = (ushort*)alloc((size_t)N_NODES * 160 * 2);
  ushort* nlat = (ushort*)alloc((size_t)N_NODES * 160 * 2);
  ushort* Qc   = (ushort*)alloc((size_t)N_NODES * 256 * 2);  // nl @ mW1[0:320]
  int* degcur  = (int*)alloc((size_t)2 * N_NODES * 4);       // deg | cur
  int* offcsr  = (int*)alloc((size_t)(N_NODES + 1) * 4);
  int* perm    = (int*)alloc((size_t)N_EDGES * 4);
  int* rs      = (int*)alloc((size_t)N_EDGES * 4);
  int* cs      = (int*)alloc((size_t)N_EDGES * 4);
  int* bsum    = (int*)alloc((size_t)128 * 4);
  ushort* BtPe = (ushort*)alloc((size_t)256 * 192 * 2);  // [encW1_r|encW1_c]^T
  ushort* BtWenc = (ushort*)alloc((size_t)128 * 64 * 2); // encW1[320:328]^T (pad 64)
  ushort* BtE2 = (ushort*)alloc((size_t)64 * 128 * 2);
  ushort* BtPQ = (ushort*)alloc((size_t)768 * 320 * 2);  // [eW1_r|eW1_c|mW1q]^T
  ushort* BtWe = (ushort*)alloc((size_t)256 * 128 * 2);  // eW1[640:768]^T
  ushort* Bte2 = (ushort*)alloc((size_t)64 * 256 * 2);
  ushort* BtWm = (ushort*)alloc((size_t)256 * 64 * 2);   // mW1[320:384]^T
  ushort* Btn1 = (ushort*)alloc((size_t)160 * 256 * 2);
  ushort* pool = (ushort*)alloc((size_t)4096 * 2);
  unsigned int* flag = (unsigned int*)alloc(64);
  ushort* msg = hm;
  ushort* eac  = (ushort*)agg;                                    // [E,8] bf16
  ushort* Penc = (ushort*)((char*)agg + (size_t)N_EDGES * 8 * 2); // [N,256] bf16
  ushort* Prc  = (ushort*)agg;                                    // [N,512] bf16
  ushort* zb   = pool + 2048;                                     // zeros

  ushort* encb1c = pool;        ushort* encb2c = pool + 128;
  ushort* eb1c   = pool + 192;  ushort* eb2c   = pool + 448;
  ushort* mb1c   = pool + 512;  ushort* attvc  = pool + 768;
  ushort* nb1c   = pool + 1024; ushort* lnngc  = pool + 1184;
  ushort* lnnbc  = pool + 1344; ushort* lnegc  = pool + 1504;
  ushort* lnebc  = pool + 1568;

  if (off > ws_size) {
    hipMemsetAsync(d_out, 0, (size_t)out_size * 2, stream);
    return;
  }

  hipMemsetAsync(flag, 0, 64, stream);
  hipMemsetAsync(pool, 0, 4096 * 2, stream);
  hipMemsetAsync(degcur, 0, (size_t)2 * N_NODES * 4, stream);

  detect_k<<<64, 256, 0, stream>>>((const ushort*)x_r, flag);

  // CSR build (edge_row is iteration-invariant); all edge buffers stored sorted.
  {
    int* deg = degcur;
    int* cur = degcur + N_NODES;
    const int nb = (N_NODES + SCAN_B - 1) / SCAN_B;  // 98
    hist_k<<<(N_EDGES + 255) / 256, 256, 0, stream>>>(erow, deg);
    scan_blk_k<<<nb, SCAN_B, 0, stream>>>(deg, offcsr, bsum, N_NODES);
    scan_top_k<<<1, 128, 0, stream>>>(bsum, nb);
    scan_add_k<<<(N_NODES + 255) / 256, 256, 0, stream>>>(offcsr, bsum, N_NODES);
    fill_k<<<(N_EDGES + 255) / 256, 256, 0, stream>>>(erow, offcsr, cur, perm);
    gather_rc_k<<<(N_EDGES + 255) / 256, 256, 0, stream>>>(erow, ecol, perm, rs, cs);
  }

  cvt_in_k<<<(N_NODES * 160 + 255) / 256, 256, 0, stream>>>(x_r, xc, N_NODES * 160, flag);
  cvt_eattr_k<<<(N_EDGES * 8 + 255) / 256, 256, 0, stream>>>(eattr_r, perm, eac, flag);
  cvt_in_k<<<1, 256, 0, stream>>>(encb1_r, encb1c, 128, flag);
  cvt_in_k<<<1, 256, 0, stream>>>(encb2_r, encb2c, 64, flag);
  cvt_in_k<<<1, 256, 0, stream>>>(eb1_r, eb1c, 256, flag);
  cvt_in_k<<<1, 256, 0, stream>>>(eb2_r, eb2c, 64, flag);
  cvt_in_k<<<1, 256, 0, stream>>>(mb1_r, mb1c, 256, flag);
  cvt_in_k<<<1, 256, 0, stream>>>(attv_r, attvc, 256, flag);
  cvt_in_k<<<1, 256, 0, stream>>>(nb1_r, nb1c, 160, flag);
  cvt_in_k<<<1, 256, 0, stream>>>(lnng_r, lnngc, 160, flag);
  cvt_in_k<<<1, 256, 0, stream>>>(lnnb_r, lnnbc, 160, flag);
  cvt_in_k<<<1, 256, 0, stream>>>(lneg_r, lnegc, 64, flag);
  cvt_in_k<<<1, 256, 0, stream>>>(lneb_r, lnebc, 64, flag);

  // weight transposes (Bt[n][k] layout, K zero-padded to multiple of 32)
  transpose2_k<<<dim3(1, 128), 256, 0, stream>>>(encW1, BtPe,             0, 160, 192, 128, flag);
  transpose2_k<<<dim3(1, 128), 256, 0, stream>>>(encW1, BtPe + 128 * 192, 160, 160, 192, 128, flag);
  transpose2_k<<<dim3(1, 128), 256, 0, stream>>>(encW1, BtWenc,           320, 8, 64, 128, flag);
  transpose2_k<<<dim3(1, 64), 256, 0, stream>>>(encW2, BtE2, 0, 128, 128, 64, flag);
  transpose2_k<<<dim3(2, 256), 256, 0, stream>>>(eW1, BtPQ,             0, 320, 320, 256, flag);
  transpose2_k<<<dim3(2, 256), 256, 0, stream>>>(eW1, BtPQ + 256 * 320, 320, 320, 320, 256, flag);
  transpose2_k<<<dim3(2, 256), 256, 0, stream>>>(mW1, BtPQ + 512 * 320, 0, 320, 320, 256, flag);
  transpose2_k<<<dim3(1, 256), 256, 0, stream>>>(eW1, BtWe, 640, 128, 128, 256, flag);
  transpose2_k<<<dim3(1, 64), 256, 0, stream>>>(eW2, Bte2, 0, 256, 256, 64, flag);
  transpose2_k<<<dim3(1, 256), 256, 0, stream>>>(mW1, BtWm, 320, 64, 64, 256, flag);
  transpose2_k<<<dim3(1, 160), 256, 0, stream>>>(nW1, Btn1, 0, 256, 256, 160, flag);

  copy_u4_k<<<(N_NODES * 160 / 8 + 255) / 256, 256, 0, stream>>>(
      (const uint4*)xc, (uint4*)nlat, N_NODES * 160 / 8);

  const int gE = (N_EDGES + 127) / 128;  // 1563
  const int gN = (N_NODES + 127) / 128;  // 391

  {  // enc pre-GEMM: Penc = x @ [encW1_r | encW1_c]   [N,256]
    GemmP p{};
    p.X = xc; p.Bt = BtPe; p.bias = zb;
    p.outb = Penc; p.ob_stride = 256;
    p.M = N_NODES; p.K = 192; p.Nw = 256;
    gemm_k<7, 0, false, 8, false, 64><<<dim3(2, gN), 256, 0, stream>>>(p);
  }
  {  // enc edge GEMM (BK=32): relu(Penc_r[rs]+Penc_c[cs] + eattr@Wenc + b) -> hm
    GemmP p{};
    p.E2 = eac; p.row = rs; p.col = cs;
    p.Cr = Penc; p.Cc = Penc + 128; p.cst = 256;
    p.Bt = BtWenc; p.bias = encb1c;
    p.outb = hm; p.ob_stride = 128;
    p.M = N_EDGES; p.K = 64; p.Nw = 128;
    gemm_k<8, 1, true, 8, false, 32><<<dim3(1, gE), 256, 0, stream>>>(p);
  }
  {  // encoder GEMM2: hm @ [128,64] -> el[:,0:64] and el[:,64:128]
    GemmP p{};
    p.E2 = hm; p.e2s = 128; p.Bt = BtE2; p.bias = encb2c;
    p.outb = el; p.ob_stride = 128;
    p.outb2 = el + 64; p.ob2_stride = 128;
    p.M = N_EDGES; p.K = 128; p.Nw = 64;
    gemm_k<0, 0, false, 4, false, 64><<<dim3(1, gE), 256, 0, stream>>>(p);
  }

  for (int it = 0; it < 3; it++) {
    {  // merged node pre-GEMM: [x|nlat] @ [eW1_r|eW1_c|mW1q] -> Prc + Qc
      GemmP p{};
      p.X = xc; p.L = nlat; p.Bt = BtPQ; p.bias = zb;
      p.outb = Prc; p.ob_stride = 512;
      p.outS = Qc; p.oS_stride = 256; p.nsplit = 512;
      p.M = N_NODES; p.K = 320; p.Nw = 768;
      gemm_k<5, 0, false, 8, false, 64><<<dim3(6, gN), 256, 0, stream>>>(p);
    }
    {  // edge GEMM1 (BK=32): relu(Pr[rs]+Pc[cs] + el@We + b) -> hm [E,256]
      GemmP p{};
      p.E2 = el; p.e2s = 128; p.row = rs; p.col = cs;
      p.Cr = Prc; p.Cc = Prc + 256; p.cst = 512;
      p.Bt = BtWe; p.bias = eb1c;
      p.outb = hm; p.ob_stride = 256;
      p.M = N_EDGES; p.K = 128; p.Nw = 256;
      gemm_k<0, 1, true, 8, false, 32><<<dim3(2, gE), 256, 0, stream>>>(p);
    }
    {  // edge GEMM2: hm @ [256,64] -> new_edge into el upper half (pre-LN)
      GemmP p{};
      p.E2 = hm; p.e2s = 256; p.Bt = Bte2; p.bias = eb2c;
      p.outb = el + 64; p.ob_stride = 128;
      p.M = N_EDGES; p.K = 256; p.Nw = 64;
      gemm_k<0, 0, false, 4, false, 64><<<dim3(1, gE), 256, 0, stream>>>(p);
    }
    {  // msg GEMM (BK=32): relu(Qc[cs] + new_edge@Wm + b) -> msg [E,256]
      GemmP p{};
      p.E2 = el + 64; p.e2s = 128; p.row = rs; p.col = cs;
      p.Cc = Qc; p.cst = 256;
      p.Bt = BtWm; p.bias = mb1c;
      p.outb = msg; p.ob_stride = 256;
      p.M = N_EDGES; p.K = 64; p.Nw = 256;
      gemm_k<0, 2, true, 8, false, 32><<<dim3(2, gE), 256, 0, stream>>>(p);
    }
    ln_edge_k<<<N_EDGES / 4, 256, 0, stream>>>(lnegc, lnebc, el);
    // fused attention softmax + aggregation (contiguous sorted segments)
    agg_csr_k<<<(N_NODES + 3) / 4, 256, 0, stream>>>(msg, attvc, offcsr, agg);
    {  // node GEMM + fused residual LayerNorm: agg@nW1 + b; LN(x + .) -> nlat
      GemmP p{};
      p.Af = agg; p.Bt = Btn1; p.bias = nb1c;
      p.X = xc; p.of_stride = 160;          // residual input + its stride
      p.Cr = lnngc; p.Cc = lnnbc;           // gamma / beta
      p.outb = nlat; p.ob_stride = 160;
      p.M = N_NODES; p.K = 256; p.Nw = 160;
      gemm_k<4, 0, false, 10, true, 64><<<dim3(1, gN), 256, 0, stream>>>(p);
    }
  }

  out_node_k<<<(N_NODES * 160 + 255) / 256, 256, 0, stream>>>(nlat, d_out, flag);
  out_edge_k<<<(N_EDGES * 64 + 255) / 256, 256, 0, stream>>>(el, perm, d_out, flag);
  (void)out_size;
}